// Round 4
// baseline (2270.800 us; speedup 1.0000x reference)
//
#include <hip/hip_runtime.h>
#include <math.h>

#define S_LEN 2048
#define DMODEL 2048
#define NHEAD 16
#define KVHEAD 2
#define DHEAD 128
#define NLAYER 4
#define VOCAB 10000
#define INNER_DIM 8192
#define LN_EPS 1e-5f
#define VOCAB_PAD 10240  // 80*128
#define QKVN 2560        // 2048 q + 256 k + 256 v

typedef __attribute__((ext_vector_type(4))) float f32x4;
typedef __attribute__((ext_vector_type(2))) float f32x2;
typedef __attribute__((ext_vector_type(8))) short s16x8;
typedef __attribute__((ext_vector_type(4))) short s16x4;

__device__ __forceinline__ short f2bf(float f) {
  union { float f; unsigned u; } v; v.f = f;
  unsigned r = v.u + 0x7FFFu + ((v.u >> 16) & 1u);  // RNE
  return (short)(r >> 16);
}

__device__ __forceinline__ float gelu_tanh(float x) {
  float x3 = x * x * x;
  return 0.5f * x * (1.0f + tanhf(0.7978845608028654f * (x + 0.044715f * x3)));
}

__device__ __forceinline__ void glds16(const void* g, void* l) {
  __builtin_amdgcn_global_load_lds(
      (const __attribute__((address_space(1))) unsigned int*)g,
      (__attribute__((address_space(3))) unsigned int*)l, 16, 0, 0);
}

// ---------------- weight transpose 64x64 tiles: W[K][N] -> WT[NP][K] bf16 --
__global__ __launch_bounds__(256)
void wtrans64(const float* __restrict__ W, short* __restrict__ WT,
              int K, int N, int NP) {
  __shared__ float ld[64][65];
  const int n0 = blockIdx.x * 64, k0 = blockIdx.y * 64;
  const int tid = threadIdx.x;
  const int rbase = tid >> 4;
  const int c4 = (tid & 15) * 4;
#pragma unroll
  for (int q = 0; q < 4; ++q) {
    int kk = rbase + q * 16;
    const float* wp = W + (size_t)(k0 + kk) * N + n0 + c4;
    float v0, v1, v2, v3;
    if (n0 + c4 + 3 < N) {
      f32x4 v = *(const f32x4*)wp;
      v0 = v[0]; v1 = v[1]; v2 = v[2]; v3 = v[3];
    } else {
      v0 = (n0 + c4 + 0 < N) ? wp[0] : 0.f;
      v1 = (n0 + c4 + 1 < N) ? wp[1] : 0.f;
      v2 = (n0 + c4 + 2 < N) ? wp[2] : 0.f;
      v3 = (n0 + c4 + 3 < N) ? wp[3] : 0.f;
    }
    ld[kk][c4 + 0] = v0; ld[kk][c4 + 1] = v1;
    ld[kk][c4 + 2] = v2; ld[kk][c4 + 3] = v3;
  }
  __syncthreads();
#pragma unroll
  for (int s = 0; s < 2; ++s) {
    int lin = tid + s * 256;
    int nn = lin >> 3;
    int ks = lin & 7;
    int n = n0 + nn;
    if (n < NP) {
      s16x8 o;
#pragma unroll
      for (int j = 0; j < 8; ++j)
        o[j] = (n < N) ? f2bf(ld[ks * 8 + j][nn]) : (short)0;
      *(s16x8*)&WT[(size_t)n * K + k0 + ks * 8] = o;
    }
  }
}

// ---------------- embedding gather ----------------
__global__ __launch_bounds__(256)
void embed_gather(const int* __restrict__ text, const float* __restrict__ ew,
                  float* __restrict__ out) {
  const int row = blockIdx.x;
  const int tok = text[row];
  const float* src = ew + (size_t)tok * DMODEL;
  float* dst = out + (size_t)row * DMODEL;
#pragma unroll
  for (int i = 0; i < 2; ++i) {
    int idx = (threadIdx.x + i * 256) * 4;
    *(f32x4*)(dst + idx) = *(const f32x4*)(src + idx);
  }
}

// ---------------- triple LayerNorm: model -> block -> attn ----------------
__global__ __launch_bounds__(256)
void ln_triple(const float* __restrict__ in,
               const float* __restrict__ mg, const float* __restrict__ mb,
               const float* __restrict__ bg, const float* __restrict__ bb,
               const float* __restrict__ ag, const float* __restrict__ ab,
               float* __restrict__ hb, short* __restrict__ hn16) {
  const int row = blockIdx.x;
  const int tid = threadIdx.x;
  const int wave = tid >> 6;
  __shared__ float rs[3][4], rs2[3][4];
  float v[8];
  const float* x = in + (size_t)row * DMODEL;
#pragma unroll
  for (int i = 0; i < 8; ++i) v[i] = x[tid + i * 256];
#pragma unroll
  for (int rnd = 0; rnd < 3; ++rnd) {
    float s = 0.f, s2 = 0.f;
#pragma unroll
    for (int i = 0; i < 8; ++i) { s += v[i]; s2 += v[i] * v[i]; }
#pragma unroll
    for (int off = 1; off < 64; off <<= 1) {
      s += __shfl_xor(s, off); s2 += __shfl_xor(s2, off);
    }
    if ((tid & 63) == 0) { rs[rnd][wave] = s; rs2[rnd][wave] = s2; }
    __syncthreads();
    s = rs[rnd][0] + rs[rnd][1] + rs[rnd][2] + rs[rnd][3];
    s2 = rs2[rnd][0] + rs2[rnd][1] + rs2[rnd][2] + rs2[rnd][3];
    const float mean = s * (1.f / DMODEL);
    const float var = s2 * (1.f / DMODEL) - mean * mean;
    const float rstd = rsqrtf(var + LN_EPS);
    const float* gg = (rnd == 0) ? mg : (rnd == 1) ? bg : ag;
    const float* bbv = (rnd == 0) ? mb : (rnd == 1) ? bb : ab;
#pragma unroll
    for (int i = 0; i < 8; ++i) {
      int idx = tid + i * 256;
      v[i] = (v[i] - mean) * rstd * gg[idx] + bbv[idx];
    }
    if (rnd == 1) {
      float* o = hb + (size_t)row * DMODEL;
#pragma unroll
      for (int i = 0; i < 8; ++i) o[tid + i * 256] = v[i];
    }
  }
  short* o = hn16 + (size_t)row * DMODEL;
#pragma unroll
  for (int i = 0; i < 8; ++i) o[tid + i * 256] = f2bf(v[i]);
}

// ---------------- dual LN (model -> head), bf16 out ----------------
__global__ __launch_bounds__(256)
void ln_dual(const float* __restrict__ in,
             const float* __restrict__ mg, const float* __restrict__ mb,
             const float* __restrict__ hg, const float* __restrict__ hbv,
             short* __restrict__ out16) {
  const int row = blockIdx.x;
  const int tid = threadIdx.x;
  const int wave = tid >> 6;
  __shared__ float rs[2][4], rs2[2][4];
  float v[8];
  const float* x = in + (size_t)row * DMODEL;
#pragma unroll
  for (int i = 0; i < 8; ++i) v[i] = x[tid + i * 256];
#pragma unroll
  for (int rnd = 0; rnd < 2; ++rnd) {
    float s = 0.f, s2 = 0.f;
#pragma unroll
    for (int i = 0; i < 8; ++i) { s += v[i]; s2 += v[i] * v[i]; }
#pragma unroll
    for (int off = 1; off < 64; off <<= 1) {
      s += __shfl_xor(s, off); s2 += __shfl_xor(s2, off);
    }
    if ((tid & 63) == 0) { rs[rnd][wave] = s; rs2[rnd][wave] = s2; }
    __syncthreads();
    s = rs[rnd][0] + rs[rnd][1] + rs[rnd][2] + rs[rnd][3];
    s2 = rs2[rnd][0] + rs2[rnd][1] + rs2[rnd][2] + rs2[rnd][3];
    const float mean = s * (1.f / DMODEL);
    const float var = s2 * (1.f / DMODEL) - mean * mean;
    const float rstd = rsqrtf(var + LN_EPS);
    const float* gg = (rnd == 0) ? mg : hg;
    const float* bbv = (rnd == 0) ? mb : hbv;
#pragma unroll
    for (int i = 0; i < 8; ++i) {
      int idx = tid + i * 256;
      v[i] = (v[i] - mean) * rstd * gg[idx] + bbv[idx];
    }
  }
  short* o = out16 + (size_t)row * DMODEL;
#pragma unroll
  for (int i = 0; i < 8; ++i) o[tid + i * 256] = f2bf(v[i]);
}

// ---------------- qk-norm on strided rows of qkv buffer -> packed bf16 ----
template<int NH>
__global__ __launch_bounds__(256)
void qknorm_s(const float* __restrict__ base, int headOff,
              const float* __restrict__ g, short* __restrict__ out, int nrows) {
  const int row = blockIdx.x * 4 + (threadIdx.x >> 6);
  const int lane = threadIdx.x & 63;
  if (row >= nrows) return;
  const int s = row / NH, h = row % NH;
  const float* p = base + (size_t)s * QKVN + headOff + h * DHEAD;
  f32x2 t = *(const f32x2*)(p + lane * 2);
  float sm = t[0] + t[1];
  float s2 = t[0] * t[0] + t[1] * t[1];
#pragma unroll
  for (int off = 1; off < 64; off <<= 1) {
    sm += __shfl_xor(sm, off); s2 += __shfl_xor(s2, off);
  }
  const float mean = sm * (1.f / DHEAD);
  const float var = s2 * (1.f / DHEAD) - mean * mean;
  const float rstd = rsqrtf(var + LN_EPS);
  short* o = out + (size_t)row * DHEAD;
  o[lane * 2] = f2bf((t[0] - mean) * rstd * g[lane * 2]);
  o[lane * 2 + 1] = f2bf((t[1] - mean) * rstd * g[lane * 2 + 1]);
}

// ---------------- v slice convert f32 -> bf16 ----------------
__global__ __launch_bounds__(256)
void vconv(const float* __restrict__ qkvf, short* __restrict__ vb16) {
  int i = blockIdx.x * 256 + threadIdx.x;
  int s = i >> 6, c4 = (i & 63) * 4;
  f32x4 v = *(const f32x4*)(qkvf + (size_t)s * QKVN + 2048 + 256 + c4);
  s16x4 o;
  o[0] = f2bf(v[0]); o[1] = f2bf(v[1]); o[2] = f2bf(v[2]); o[3] = f2bf(v[3]);
  *(s16x4*)&vb16[(size_t)s * 256 + c4] = o;
}

// ---------------- 4-stage deep-pipelined bf16 GEMM -----------------------
// C[M,N] = act(A[M,K] @ BT[N,K]^T + bias) (+res). 128x128 tile, BK=32,
// 4 LDS stages, depth-3 prefetch, counted vmcnt (never 0 in steady state),
// ONE raw s_barrier per K-step, setprio around MFMA, XCD-swizzled grid.
template<int ACT, bool BIAS, bool RES, bool WF, bool WB>
__global__ __launch_bounds__(256, 2)
void gemm_p4(const short* __restrict__ A, const short* __restrict__ BT,
             const float* __restrict__ bias, const float* __restrict__ res,
             float* __restrict__ Cf, short* __restrict__ Cb,
             int M, int N, int K) {
  __shared__ short As[4][128 * 32];   // 8KB per stage per operand
  __shared__ short Bs[4][128 * 32];   // total 64KB -> 2 blocks/CU
  const int tid = threadIdx.x;
  const int wave = tid >> 6, lane = tid & 63;
  const int g = lane >> 4, r = lane & 15;
  const int wm = wave >> 1, wn = wave & 1;

  // XCD-aware bijective swizzle (all grids have nwg % 8 == 0)
  const int GY = gridDim.y;
  int lin = blockIdx.x + blockIdx.y * gridDim.x;
  int nwg = gridDim.x * GY;
  int sw = ((nwg & 7) == 0) ? ((lin & 7) * (nwg >> 3) + (lin >> 3)) : lin;
  const int bm = (sw % GY) * 128;
  const int bn = (sw / GY) * 128;

  // staging sources: chunk c = i*256+tid; row=c>>2, 16B-slot=c&3,
  // pre-swizzled global col so linear LDS + swizzled ds_read match (rule #21)
  const short* ga[2]; const short* gb[2]; int lo[2];
#pragma unroll
  for (int i = 0; i < 2; ++i) {
    int c = i * 256 + tid;
    int row = c >> 2, slot = c & 3;
    int col = ((slot ^ ((row >> 1) & 3)) << 3);
    ga[i] = A + (size_t)(bm + row) * K + col;
    gb[i] = BT + (size_t)(bn + row) * K + col;
    lo[i] = (i * 256 + (wave << 6)) << 3;  // shorts; HW adds lane*16B
  }
  const int NT = K >> 5;

  // prologue: stage tiles 0,1,2 (12 loads in flight per wave)
#pragma unroll
  for (int t = 0; t < 3; ++t) {
#pragma unroll
    for (int i = 0; i < 2; ++i) {
      glds16(ga[i] + t * 32, &As[t][lo[i]]);
      glds16(gb[i] + t * 32, &Bs[t][lo[i]]);
    }
  }

  f32x4 acc[4][4] = {};
  for (int t = 0; t < NT; ++t) {
    const int rem = NT - 1 - t;
    if (rem >= 2)      asm volatile("s_waitcnt vmcnt(8)" ::: "memory");
    else if (rem == 1) asm volatile("s_waitcnt vmcnt(4)" ::: "memory");
    else               asm volatile("s_waitcnt vmcnt(0)" ::: "memory");
    asm volatile("s_barrier" ::: "memory");  // all waves' tile-t loads landed
    const short* as = As[t & 3];
    const short* bs = Bs[t & 3];
    s16x8 af[4], bf[4];
#pragma unroll
    for (int m = 0; m < 4; ++m) {
      int rr = wm * 64 + m * 16 + r;
      af[m] = *(const s16x8*)&as[rr * 32 + ((g ^ ((rr >> 1) & 3)) << 3)];
    }
#pragma unroll
    for (int n = 0; n < 4; ++n) {
      int rr = wn * 64 + n * 16 + r;
      bf[n] = *(const s16x8*)&bs[rr * 32 + ((g ^ ((rr >> 1) & 3)) << 3)];
    }
    if (t + 3 < NT) {
#pragma unroll
      for (int i = 0; i < 2; ++i) {
        glds16(ga[i] + (t + 3) * 32, &As[(t + 3) & 3][lo[i]]);
        glds16(gb[i] + (t + 3) * 32, &Bs[(t + 3) & 3][lo[i]]);
      }
    }
    asm volatile("s_waitcnt lgkmcnt(0)" ::: "memory");
    __builtin_amdgcn_sched_barrier(0);
    __builtin_amdgcn_s_setprio(1);
#pragma unroll
    for (int m = 0; m < 4; ++m)
#pragma unroll
      for (int n = 0; n < 4; ++n)
        acc[m][n] = __builtin_amdgcn_mfma_f32_16x16x32_bf16(af[m], bf[n], acc[m][n], 0, 0, 0);
    __builtin_amdgcn_s_setprio(0);
  }

  // epilogue: C col=lane&15, row=(lane>>4)*4+j
#pragma unroll
  for (int m = 0; m < 4; ++m) {
    int row = bm + wm * 64 + m * 16 + g * 4;
#pragma unroll
    for (int n = 0; n < 4; ++n) {
      int col = bn + wn * 64 + n * 16 + r;
      if (col < N) {
#pragma unroll
        for (int j = 0; j < 4; ++j) {
          float v = acc[m][n][j];
          if (BIAS) v += bias[col];
          if (ACT) v = gelu_tanh(v);
          if (RES) v += res[(size_t)(row + j) * N + col];
          if (WF) Cf[(size_t)(row + j) * N + col] = v;
          if (WB) Cb[(size_t)(row + j) * N + col] = f2bf(v);
        }
      }
    }
  }
}

// ---------------- Flash attention (causal, GQA), bf16 in/out -------------
__global__ __launch_bounds__(256)
void attn_fwd(const short* __restrict__ qbuf, const short* __restrict__ kbuf,
              const short* __restrict__ vbuf, short* __restrict__ obuf) {
  __shared__ short Qs[64][136];
  __shared__ short Ks[32][136];
  __shared__ short Vt[128][40];   // [d][j ^ f(d)], f(d)=((d>>3)&3)<<3
  __shared__ short Ps[4][16][40];
  const int tid = threadIdx.x;
  int lin = blockIdx.x + blockIdx.y * gridDim.x;  // 32 x 16 grid
  int sw = (lin & 7) * 64 + (lin >> 3);
  const int qbase = (sw & 31) * 64;
  const int h = sw >> 5;
  const int kh = h >> 3;
  const int wave = tid >> 6;
  const int lane = tid & 63;
  const int g = lane >> 4;
  const int r = lane & 15;

#pragma unroll
  for (int i = 0; i < 4; ++i) {
    int idx = tid + i * 256;
    int row = idx >> 4;
    int c8 = (idx & 15) << 3;
    s16x8 v = *(const s16x8*)(qbuf + (size_t)(qbase + row) * DMODEL + h * DHEAD + c8);
    *(s16x8*)&Qs[row][c8] = v;
  }

  f32x4 O[8];
#pragma unroll
  for (int d = 0; d < 8; ++d) O[d] = (f32x4){0.f, 0.f, 0.f, 0.f};
  float mst[4], lst[4];
#pragma unroll
  for (int j = 0; j < 4; ++j) { mst[j] = -1e30f; lst[j] = 0.f; }
  const int nt = (qbase + 64) >> 5;
  const int qrow0 = qbase + wave * 16;

  for (int jt = 0; jt < nt; ++jt) {
    const int jb = jt * 32;
    __syncthreads();
#pragma unroll
    for (int i = 0; i < 2; ++i) {
      int idx = tid + i * 256;
      int row = idx >> 4;
      int c8 = (idx & 15) << 3;
      s16x8 kv = *(const s16x8*)(kbuf + (size_t)(jb + row) * (KVHEAD * DHEAD) + kh * DHEAD + c8);
      *(s16x8*)&Ks[row][c8] = kv;
      s16x8 vv = *(const s16x8*)(vbuf + (size_t)(jb + row) * (KVHEAD * DHEAD) + kh * DHEAD + c8);
#pragma unroll
      for (int u = 0; u < 8; ++u) {
        int d = c8 + u;
        Vt[d][row ^ (((d >> 3) & 3) << 3)] = vv[u];
      }
    }
    __syncthreads();

    f32x4 sc[2];
    sc[0] = (f32x4){0.f, 0.f, 0.f, 0.f};
    sc[1] = (f32x4){0.f, 0.f, 0.f, 0.f};
    __builtin_amdgcn_s_setprio(1);
#pragma unroll
    for (int n = 0; n < 2; ++n)
#pragma unroll
      for (int kc = 0; kc < 4; ++kc) {
        s16x8 a = *(const s16x8*)&Qs[wave * 16 + r][kc * 32 + g * 8];
        s16x8 bb = *(const s16x8*)&Ks[n * 16 + r][kc * 32 + g * 8];
        sc[n] = __builtin_amdgcn_mfma_f32_16x16x32_bf16(a, bb, sc[n], 0, 0, 0);
      }
    __builtin_amdgcn_s_setprio(0);
    const float scale = 0.08838834764831845f;
    float pmax[4];
#pragma unroll
    for (int j = 0; j < 4; ++j) {
      int irow = qrow0 + g * 4 + j;
#pragma unroll
      for (int n = 0; n < 2; ++n) {
        int jcol = jb + n * 16 + r;
        sc[n][j] = (jcol <= irow) ? sc[n][j] * scale : -1e30f;
      }
      pmax[j] = fmaxf(sc[0][j], sc[1][j]);
    }
#pragma unroll
    for (int off = 1; off < 16; off <<= 1)
#pragma unroll
      for (int j = 0; j < 4; ++j) pmax[j] = fmaxf(pmax[j], __shfl_xor(pmax[j], off));

    float alpha[4], rsum[4];
#pragma unroll
    for (int j = 0; j < 4; ++j) {
      float mnew = fmaxf(mst[j], pmax[j]);
      alpha[j] = __expf(mst[j] - mnew);
      mst[j] = mnew;
      sc[0][j] = __expf(sc[0][j] - mnew);
      sc[1][j] = __expf(sc[1][j] - mnew);
      rsum[j] = sc[0][j] + sc[1][j];
    }
#pragma unroll
    for (int off = 1; off < 16; off <<= 1)
#pragma unroll
      for (int j = 0; j < 4; ++j) rsum[j] += __shfl_xor(rsum[j], off);
#pragma unroll
    for (int j = 0; j < 4; ++j) lst[j] = lst[j] * alpha[j] + rsum[j];
#pragma unroll
    for (int d = 0; d < 8; ++d)
#pragma unroll
      for (int j = 0; j < 4; ++j) O[d][j] *= alpha[j];
#pragma unroll
    for (int j = 0; j < 4; ++j) {
      Ps[wave][g * 4 + j][r] = f2bf(sc[0][j]);
      Ps[wave][g * 4 + j][16 + r] = f2bf(sc[1][j]);
    }
    s16x8 a = *(const s16x8*)&Ps[wave][r][g * 8];
    __builtin_amdgcn_s_setprio(1);
#pragma unroll
    for (int d = 0; d < 8; ++d) {
      int dd = d * 16 + r;
      s16x8 bb = *(const s16x8*)&Vt[dd][(g << 3) ^ (((dd >> 3) & 3) << 3)];
      O[d] = __builtin_amdgcn_mfma_f32_16x16x32_bf16(a, bb, O[d], 0, 0, 0);
    }
    __builtin_amdgcn_s_setprio(0);
  }
  float linv[4];
#pragma unroll
  for (int j = 0; j < 4; ++j) linv[j] = 1.f / lst[j];
#pragma unroll
  for (int d = 0; d < 8; ++d)
#pragma unroll
    for (int j = 0; j < 4; ++j)
      obuf[(size_t)(qrow0 + g * 4 + j) * DMODEL + h * DHEAD + d * 16 + r] =
          f2bf(O[d][j] * linv[j]);
}

// ---------------- host side ----------------
extern "C" void kernel_launch(void* const* d_in, const int* in_sizes, int n_in,
                              void* d_out, int out_size, void* d_ws, size_t ws_size,
                              hipStream_t stream) {
  const int* text = (const int*)d_in[0];
  const float* embed_w = (const float*)d_in[1];
  const float* model_g = (const float*)d_in[2];
  const float* model_b = (const float*)d_in[3];
  const float* blk_g = (const float*)d_in[4];
  const float* blk_b = (const float*)d_in[5];
  const float* attn_g = (const float*)d_in[6];
  const float* attn_b = (const float*)d_in[7];
  const float* wq = (const float*)d_in[8];
  const float* wk = (const float*)d_in[9];
  const float* wv = (const float*)d_in[10];
  const float* wo = (const float*)d_in[11];
  const float* qn_g = (const float*)d_in[12];
  const float* kn_g = (const float*)d_in[13];
  const float* w1 = (const float*)d_in[14];
  const float* b1 = (const float*)d_in[15];
  const float* w2 = (const float*)d_in[16];
  const float* b2 = (const float*)d_in[17];
  const float* head_g = (const float*)d_in[18];
  const float* head_b = (const float*)d_in[19];
  const float* head_w = (const float*)d_in[20];
  const float* head_bias = (const float*)d_in[21];
  float* out = (float*)d_out;

  const size_t SD = (size_t)S_LEN * DMODEL;
  const size_t SKV = (size_t)S_LEN * KVHEAD * DHEAD;
  const size_t SI = (size_t)S_LEN * INNER_DIM;
  const size_t WD = (size_t)DMODEL * DMODEL;
  const size_t WKV = (size_t)DMODEL * KVHEAD * DHEAD;
  const size_t WI = (size_t)DMODEL * INNER_DIM;

  char* p = (char*)d_ws;
  float* xres  = (float*)p; p += SD * 4;
  float* hb    = (float*)p; p += SD * 4;
  float* h2    = (float*)p; p += SD * 4;
  float* qkvf  = (float*)p; p += (size_t)S_LEN * QKVN * 4;
  short* hn16  = (short*)p; p += SD * 2;
  short* h216  = (short*)p; p += SD * 2;
  short* ao16  = (short*)p; p += SD * 2;
  short* ffi16 = (short*)p; p += SI * 2;
  short* qb16  = (short*)p; p += SD * 2;
  short* kb16  = (short*)p; p += SKV * 2;
  short* vb16  = (short*)p; p += SKV * 2;
  short* wqkvT = (short*)p; p += (size_t)QKVN * DMODEL * 2;
  short* woT   = (short*)p; p += WD * 2;
  short* w1T   = (short*)p; p += WI * 2;
  short* w2T   = (short*)p; p += WI * 2;
  short* headT = w1T;  // reused after layers (10240*2048*2 = 42MB < 64MB)

  dim3 blk(256);
  embed_gather<<<S_LEN, blk, 0, stream>>>(text, embed_w, xres);

  for (int i = 0; i < NLAYER; ++i) {
    const float* wq_i = wq + (size_t)i * WD;
    const float* wk_i = wk + (size_t)i * WKV;
    const float* wv_i = wv + (size_t)i * WKV;
    const float* wo_i = wo + (size_t)i * WD;
    const float* w1_i = w1 + (size_t)i * WI;
    const float* b1_i = b1 + (size_t)i * INNER_DIM;
    const float* w2_i = w2 + (size_t)i * WI;
    const float* b2_i = b2 + (size_t)i * DMODEL;

    wtrans64<<<dim3(32, 32), blk, 0, stream>>>(wq_i, wqkvT, DMODEL, DMODEL, DMODEL);
    wtrans64<<<dim3(4, 32), blk, 0, stream>>>(wk_i, wqkvT + (size_t)2048 * DMODEL, DMODEL, 256, 256);
    wtrans64<<<dim3(4, 32), blk, 0, stream>>>(wv_i, wqkvT + (size_t)2304 * DMODEL, DMODEL, 256, 256);
    wtrans64<<<dim3(32, 32), blk, 0, stream>>>(wo_i, woT, DMODEL, DMODEL, DMODEL);
    wtrans64<<<dim3(128, 32), blk, 0, stream>>>(w1_i, w1T, DMODEL, INNER_DIM, INNER_DIM);
    wtrans64<<<dim3(32, 128), blk, 0, stream>>>(w2_i, w2T, INNER_DIM, DMODEL, DMODEL);

    ln_triple<<<S_LEN, blk, 0, stream>>>(xres, model_g, model_b,
                                         blk_g + i * DMODEL, blk_b + i * DMODEL,
                                         attn_g + i * DMODEL, attn_b + i * DMODEL,
                                         hb, hn16);

    gemm_p4<0, false, false, true, false>
        <<<dim3(QKVN / 128, S_LEN / 128), blk, 0, stream>>>(
        hn16, wqkvT, nullptr, nullptr, qkvf, nullptr, S_LEN, QKVN, DMODEL);

    qknorm_s<NHEAD><<<(S_LEN * NHEAD) / 4, blk, 0, stream>>>(
        qkvf, 0, qn_g + i * DHEAD, qb16, S_LEN * NHEAD);
    qknorm_s<KVHEAD><<<(S_LEN * KVHEAD) / 4, blk, 0, stream>>>(
        qkvf, 2048, kn_g + i * DHEAD, kb16, S_LEN * KVHEAD);
    vconv<<<(S_LEN * 64) / 256, blk, 0, stream>>>(qkvf, vb16);

    attn_fwd<<<dim3(S_LEN / 64, NHEAD), blk, 0, stream>>>(qb16, kb16, vb16, ao16);

    gemm_p4<0, false, true, true, true>
        <<<dim3(DMODEL / 128, S_LEN / 128), blk, 0, stream>>>(
        ao16, woT, nullptr, hb, h2, h216, S_LEN, DMODEL, DMODEL);
    gemm_p4<1, true, false, false, true>
        <<<dim3(INNER_DIM / 128, S_LEN / 128), blk, 0, stream>>>(
        h216, w1T, b1_i, nullptr, nullptr, ffi16, S_LEN, INNER_DIM, DMODEL);
    gemm_p4<0, true, true, true, false>
        <<<dim3(DMODEL / 128, S_LEN / 128), blk, 0, stream>>>(
        ffi16, w2T, b2_i, h2, xres, nullptr, S_LEN, DMODEL, INNER_DIM);
  }

  wtrans64<<<dim3(VOCAB_PAD / 64, 32), blk, 0, stream>>>(head_w, headT, DMODEL, VOCAB, VOCAB_PAD);
  ln_dual<<<S_LEN, blk, 0, stream>>>(xres, model_g, model_b, head_g, head_b, hn16);
  gemm_p4<0, true, false, true, false>
      <<<dim3(VOCAB_PAD / 128, S_LEN / 128), blk, 0, stream>>>(
      hn16, headT, head_bias, nullptr, out, nullptr, S_LEN, VOCAB, DMODEL);
}

// Round 5
// 2186.070 us; speedup vs baseline: 1.0388x; 1.0388x over previous
//
#include <hip/hip_runtime.h>
#include <math.h>

#define S_LEN 2048
#define DMODEL 2048
#define NHEAD 16
#define KVHEAD 2
#define DHEAD 128
#define NLAYER 4
#define VOCAB 10000
#define INNER_DIM 8192
#define LN_EPS 1e-5f
#define VOCAB_PAD 10240  // 40*256
#define QKVN 2560        // 2048 q + 256 k + 256 v

typedef __attribute__((ext_vector_type(4))) float f32x4;
typedef __attribute__((ext_vector_type(2))) float f32x2;
typedef __attribute__((ext_vector_type(8))) short s16x8;
typedef __attribute__((ext_vector_type(4))) short s16x4;

__device__ __forceinline__ short f2bf(float f) {
  union { float f; unsigned u; } v; v.f = f;
  unsigned r = v.u + 0x7FFFu + ((v.u >> 16) & 1u);  // RNE
  return (short)(r >> 16);
}

__device__ __forceinline__ float gelu_tanh(float x) {
  float x3 = x * x * x;
  return 0.5f * x * (1.0f + tanhf(0.7978845608028654f * (x + 0.044715f * x3)));
}

__device__ __forceinline__ void glds16(const void* g, void* l) {
  __builtin_amdgcn_global_load_lds(
      (const __attribute__((address_space(1))) unsigned int*)g,
      (__attribute__((address_space(3))) unsigned int*)l, 16, 0, 0);
}

// ---------------- weight transpose 64x64 tiles: W[K][N] -> WT[NP][K] bf16 --
__global__ __launch_bounds__(256)
void wtrans64(const float* __restrict__ W, short* __restrict__ WT,
              int K, int N, int NP) {
  __shared__ float ld[64][65];
  const int n0 = blockIdx.x * 64, k0 = blockIdx.y * 64;
  const int tid = threadIdx.x;
  const int rbase = tid >> 4;
  const int c4 = (tid & 15) * 4;
#pragma unroll
  for (int q = 0; q < 4; ++q) {
    int kk = rbase + q * 16;
    const float* wp = W + (size_t)(k0 + kk) * N + n0 + c4;
    float v0, v1, v2, v3;
    if (n0 + c4 + 3 < N) {
      f32x4 v = *(const f32x4*)wp;
      v0 = v[0]; v1 = v[1]; v2 = v[2]; v3 = v[3];
    } else {
      v0 = (n0 + c4 + 0 < N) ? wp[0] : 0.f;
      v1 = (n0 + c4 + 1 < N) ? wp[1] : 0.f;
      v2 = (n0 + c4 + 2 < N) ? wp[2] : 0.f;
      v3 = (n0 + c4 + 3 < N) ? wp[3] : 0.f;
    }
    ld[kk][c4 + 0] = v0; ld[kk][c4 + 1] = v1;
    ld[kk][c4 + 2] = v2; ld[kk][c4 + 3] = v3;
  }
  __syncthreads();
#pragma unroll
  for (int s = 0; s < 2; ++s) {
    int lin = tid + s * 256;
    int nn = lin >> 3;
    int ks = lin & 7;
    int n = n0 + nn;
    if (n < NP) {
      s16x8 o;
#pragma unroll
      for (int j = 0; j < 8; ++j)
        o[j] = (n < N) ? f2bf(ld[ks * 8 + j][nn]) : (short)0;
      *(s16x8*)&WT[(size_t)n * K + k0 + ks * 8] = o;
    }
  }
}

// ---------------- embedding gather ----------------
__global__ __launch_bounds__(256)
void embed_gather(const int* __restrict__ text, const float* __restrict__ ew,
                  float* __restrict__ out) {
  const int row = blockIdx.x;
  const int tok = text[row];
  const float* src = ew + (size_t)tok * DMODEL;
  float* dst = out + (size_t)row * DMODEL;
#pragma unroll
  for (int i = 0; i < 2; ++i) {
    int idx = (threadIdx.x + i * 256) * 4;
    *(f32x4*)(dst + idx) = *(const f32x4*)(src + idx);
  }
}

// ---------------- triple LayerNorm: model -> block -> attn ----------------
__global__ __launch_bounds__(256)
void ln_triple(const float* __restrict__ in,
               const float* __restrict__ mg, const float* __restrict__ mb,
               const float* __restrict__ bg, const float* __restrict__ bb,
               const float* __restrict__ ag, const float* __restrict__ ab,
               float* __restrict__ hb, short* __restrict__ hn16) {
  const int row = blockIdx.x;
  const int tid = threadIdx.x;
  const int wave = tid >> 6;
  __shared__ float rs[3][4], rs2[3][4];
  float v[8];
  const float* x = in + (size_t)row * DMODEL;
#pragma unroll
  for (int i = 0; i < 8; ++i) v[i] = x[tid + i * 256];
#pragma unroll
  for (int rnd = 0; rnd < 3; ++rnd) {
    float s = 0.f, s2 = 0.f;
#pragma unroll
    for (int i = 0; i < 8; ++i) { s += v[i]; s2 += v[i] * v[i]; }
#pragma unroll
    for (int off = 1; off < 64; off <<= 1) {
      s += __shfl_xor(s, off); s2 += __shfl_xor(s2, off);
    }
    if ((tid & 63) == 0) { rs[rnd][wave] = s; rs2[rnd][wave] = s2; }
    __syncthreads();
    s = rs[rnd][0] + rs[rnd][1] + rs[rnd][2] + rs[rnd][3];
    s2 = rs2[rnd][0] + rs2[rnd][1] + rs2[rnd][2] + rs2[rnd][3];
    const float mean = s * (1.f / DMODEL);
    const float var = s2 * (1.f / DMODEL) - mean * mean;
    const float rstd = rsqrtf(var + LN_EPS);
    const float* gg = (rnd == 0) ? mg : (rnd == 1) ? bg : ag;
    const float* bbv = (rnd == 0) ? mb : (rnd == 1) ? bb : ab;
#pragma unroll
    for (int i = 0; i < 8; ++i) {
      int idx = tid + i * 256;
      v[i] = (v[i] - mean) * rstd * gg[idx] + bbv[idx];
    }
    if (rnd == 1) {
      float* o = hb + (size_t)row * DMODEL;
#pragma unroll
      for (int i = 0; i < 8; ++i) o[tid + i * 256] = v[i];
    }
  }
  short* o = hn16 + (size_t)row * DMODEL;
#pragma unroll
  for (int i = 0; i < 8; ++i) o[tid + i * 256] = f2bf(v[i]);
}

// ---------------- dual LN (model -> head), bf16 out ----------------
__global__ __launch_bounds__(256)
void ln_dual(const float* __restrict__ in,
             const float* __restrict__ mg, const float* __restrict__ mb,
             const float* __restrict__ hg, const float* __restrict__ hbv,
             short* __restrict__ out16) {
  const int row = blockIdx.x;
  const int tid = threadIdx.x;
  const int wave = tid >> 6;
  __shared__ float rs[2][4], rs2[2][4];
  float v[8];
  const float* x = in + (size_t)row * DMODEL;
#pragma unroll
  for (int i = 0; i < 8; ++i) v[i] = x[tid + i * 256];
#pragma unroll
  for (int rnd = 0; rnd < 2; ++rnd) {
    float s = 0.f, s2 = 0.f;
#pragma unroll
    for (int i = 0; i < 8; ++i) { s += v[i]; s2 += v[i] * v[i]; }
#pragma unroll
    for (int off = 1; off < 64; off <<= 1) {
      s += __shfl_xor(s, off); s2 += __shfl_xor(s2, off);
    }
    if ((tid & 63) == 0) { rs[rnd][wave] = s; rs2[rnd][wave] = s2; }
    __syncthreads();
    s = rs[rnd][0] + rs[rnd][1] + rs[rnd][2] + rs[rnd][3];
    s2 = rs2[rnd][0] + rs2[rnd][1] + rs2[rnd][2] + rs2[rnd][3];
    const float mean = s * (1.f / DMODEL);
    const float var = s2 * (1.f / DMODEL) - mean * mean;
    const float rstd = rsqrtf(var + LN_EPS);
    const float* gg = (rnd == 0) ? mg : hg;
    const float* bbv = (rnd == 0) ? mb : hbv;
#pragma unroll
    for (int i = 0; i < 8; ++i) {
      int idx = tid + i * 256;
      v[i] = (v[i] - mean) * rstd * gg[idx] + bbv[idx];
    }
  }
  short* o = out16 + (size_t)row * DMODEL;
#pragma unroll
  for (int i = 0; i < 8; ++i) o[tid + i * 256] = f2bf(v[i]);
}

// ---------------- qk-norm on strided rows of qkv buffer -> packed bf16 ----
template<int NH>
__global__ __launch_bounds__(256)
void qknorm_s(const float* __restrict__ base, int headOff,
              const float* __restrict__ g, short* __restrict__ out, int nrows) {
  const int row = blockIdx.x * 4 + (threadIdx.x >> 6);
  const int lane = threadIdx.x & 63;
  if (row >= nrows) return;
  const int s = row / NH, h = row % NH;
  const float* p = base + (size_t)s * QKVN + headOff + h * DHEAD;
  f32x2 t = *(const f32x2*)(p + lane * 2);
  float sm = t[0] + t[1];
  float s2 = t[0] * t[0] + t[1] * t[1];
#pragma unroll
  for (int off = 1; off < 64; off <<= 1) {
    sm += __shfl_xor(sm, off); s2 += __shfl_xor(s2, off);
  }
  const float mean = sm * (1.f / DHEAD);
  const float var = s2 * (1.f / DHEAD) - mean * mean;
  const float rstd = rsqrtf(var + LN_EPS);
  short* o = out + (size_t)row * DHEAD;
  o[lane * 2] = f2bf((t[0] - mean) * rstd * g[lane * 2]);
  o[lane * 2 + 1] = f2bf((t[1] - mean) * rstd * g[lane * 2 + 1]);
}

// ---------------- v slice convert f32 -> bf16 ----------------
__global__ __launch_bounds__(256)
void vconv(const float* __restrict__ qkvf, short* __restrict__ vb16) {
  int i = blockIdx.x * 256 + threadIdx.x;
  int s = i >> 6, c4 = (i & 63) * 4;
  f32x4 v = *(const f32x4*)(qkvf + (size_t)s * QKVN + 2048 + 256 + c4);
  s16x4 o;
  o[0] = f2bf(v[0]); o[1] = f2bf(v[1]); o[2] = f2bf(v[2]); o[3] = f2bf(v[3]);
  *(s16x4*)&vb16[(size_t)s * 256 + c4] = o;
}

// ---------------- 2-phase double-buffered bf16 GEMM (R3, proven) ---------
template<int BM, int BN, int BK, int WM, int WN, int ACT, bool BIAS, bool RES,
         bool WF, bool WB>
__global__ __launch_bounds__(WM * WN * 64)
void gemm_db(const short* __restrict__ A, const short* __restrict__ BT,
             const float* __restrict__ bias, const float* __restrict__ res,
             float* __restrict__ Cf, short* __restrict__ Cb,
             int M, int N, int K) {
  constexpr int THREADS = WM * WN * 64;
  constexpr int MR = BM / WM / 16;
  constexpr int NR = BN / WN / 16;
  constexpr int KH = BK / 32;
  constexpr int SLOTS = BK / 8;
  constexpr int SMASK = SLOTS - 1;
  constexpr int RSH = (SLOTS == 8) ? 0 : 1;
  constexpr int CSH = (SLOTS == 8) ? 3 : 2;
  constexpr int NI = (BM * BK) / (THREADS * 8);
  __shared__ short As[2][BM * BK];
  __shared__ short Bs[2][BN * BK];
  const int tid = threadIdx.x;
  const int wave = tid >> 6, lane = tid & 63;
  const int g = lane >> 4, r = lane & 15;
  const int wm = wave / WN, wn = wave % WN;

  const int GY = gridDim.y;
  int lin = blockIdx.x + blockIdx.y * gridDim.x;
  int nwg = gridDim.x * GY;
  int sw = ((nwg & 7) == 0) ? ((lin & 7) * (nwg >> 3) + (lin >> 3)) : lin;
  const int bm = (sw % GY) * BM;
  const int bn = (sw / GY) * BN;

  const short* gsrc[2 * NI];
  short* ldst[2][2 * NI];
#pragma unroll
  for (int i = 0; i < NI; ++i) {
    int c = i * THREADS + tid;
    int row = c >> CSH;
    int slot = c & SMASK;
    int col = ((slot ^ ((row >> RSH) & SMASK)) << 3);
    gsrc[i] = A + (size_t)(bm + row) * K + col;
    gsrc[NI + i] = BT + (size_t)(bn + row) * K + col;
    int base = (i * THREADS + (wave << 6)) << 3;
    ldst[0][i] = &As[0][base]; ldst[0][NI + i] = &Bs[0][base];
    ldst[1][i] = &As[1][base]; ldst[1][NI + i] = &Bs[1][base];
  }

  f32x4 acc[MR][NR] = {};
  const int NT = K / BK;

#pragma unroll
  for (int i = 0; i < 2 * NI; ++i) glds16(gsrc[i], ldst[0][i]);
  asm volatile("s_waitcnt vmcnt(0)" ::: "memory");
  __syncthreads();

  for (int t = 0; t < NT; ++t) {
    const int cur = t & 1;
    const short* as = As[cur];
    const short* bs = Bs[cur];
    s16x8 bfr[NR][KH], af[MR / 2][KH];
#pragma unroll
    for (int n = 0; n < NR; ++n) {
      int rr = wn * (NR * 16) + n * 16 + r;
#pragma unroll
      for (int kk = 0; kk < KH; ++kk) {
        int lg = kk * 4 + g;
        bfr[n][kk] = *(const s16x8*)&bs[rr * BK + ((lg ^ ((rr >> RSH) & SMASK)) << 3)];
      }
    }
#pragma unroll
    for (int mm = 0; mm < MR / 2; ++mm) {
      int rr = wm * (MR * 16) + mm * 16 + r;
#pragma unroll
      for (int kk = 0; kk < KH; ++kk) {
        int lg = kk * 4 + g;
        af[mm][kk] = *(const s16x8*)&as[rr * BK + ((lg ^ ((rr >> RSH) & SMASK)) << 3)];
      }
    }
    if (t + 1 < NT) {
#pragma unroll
      for (int i = 0; i < 2 * NI; ++i) glds16(gsrc[i] + (t + 1) * BK, ldst[cur ^ 1][i]);
    }
    asm volatile("s_waitcnt lgkmcnt(0)" ::: "memory");
    __builtin_amdgcn_sched_barrier(0);
    __builtin_amdgcn_s_setprio(1);
#pragma unroll
    for (int mm = 0; mm < MR / 2; ++mm)
#pragma unroll
      for (int n = 0; n < NR; ++n)
#pragma unroll
        for (int kk = 0; kk < KH; ++kk)
          acc[mm][n] = __builtin_amdgcn_mfma_f32_16x16x32_bf16(af[mm][kk], bfr[n][kk], acc[mm][n], 0, 0, 0);
    __builtin_amdgcn_s_setprio(0);
    __builtin_amdgcn_s_barrier();
#pragma unroll
    for (int mm = 0; mm < MR / 2; ++mm) {
      int rr = wm * (MR * 16) + (MR / 2 + mm) * 16 + r;
#pragma unroll
      for (int kk = 0; kk < KH; ++kk) {
        int lg = kk * 4 + g;
        af[mm][kk] = *(const s16x8*)&as[rr * BK + ((lg ^ ((rr >> RSH) & SMASK)) << 3)];
      }
    }
    asm volatile("s_waitcnt lgkmcnt(0)" ::: "memory");
    __builtin_amdgcn_sched_barrier(0);
    __builtin_amdgcn_s_setprio(1);
#pragma unroll
    for (int mm = 0; mm < MR / 2; ++mm)
#pragma unroll
      for (int n = 0; n < NR; ++n)
#pragma unroll
        for (int kk = 0; kk < KH; ++kk)
          acc[MR / 2 + mm][n] = __builtin_amdgcn_mfma_f32_16x16x32_bf16(af[mm][kk], bfr[n][kk], acc[MR / 2 + mm][n], 0, 0, 0);
    __builtin_amdgcn_s_setprio(0);
    __syncthreads();
  }

#pragma unroll
  for (int m = 0; m < MR; ++m) {
    int row = bm + wm * (MR * 16) + m * 16 + g * 4;
#pragma unroll
    for (int n = 0; n < NR; ++n) {
      int col = bn + wn * (NR * 16) + n * 16 + r;
      if (col < N) {
#pragma unroll
        for (int j = 0; j < 4; ++j) {
          float v = acc[m][n][j];
          if (BIAS) v += bias[col];
          if (ACT) v = gelu_tanh(v);
          if (RES) v += res[(size_t)(row + j) * N + col];
          if (WF) Cf[(size_t)(row + j) * N + col] = v;
          if (WB) Cb[(size_t)(row + j) * N + col] = f2bf(v);
        }
      }
    }
  }
}

// ---------------- 8-phase 256x256 bf16 GEMM (m201 template port) ---------
// 8 waves (2M x 4N), 512 thr, BK=64, LDS 128KB: [dbuf][half][128*64] per op.
// Per phase: ds-read subtile | stage 1 half-tile | lgkm0+schedbar | setprio
// 16 MFMA | vmcnt(2) gate at phases 3/7 only | s_barrier.
template<int ACT, bool BIAS, bool WF, bool WB>
__global__ __launch_bounds__(512, 2)
void gemm_8ph(const short* __restrict__ A, const short* __restrict__ BT,
              const float* __restrict__ bias,
              float* __restrict__ Cf, short* __restrict__ Cb,
              int M, int N, int K) {
  __shared__ short As[2][2][128 * 64];
  __shared__ short Bs[2][2][128 * 64];
  const int tid = threadIdx.x;
  const int wave = tid >> 6, lane = tid & 63;
  const int g = lane >> 4, r = lane & 15;
  const int wm = wave >> 2, wn = wave & 3;

  const int GY = gridDim.y;
  int lin = blockIdx.x + blockIdx.y * gridDim.x;
  int nwg = gridDim.x * GY;
  int sw = (lin & 7) * (nwg >> 3) + (lin >> 3);  // nwg % 8 == 0 for all grids
  const int bm = (sw % GY) * 256;
  const int bn = (sw / GY) * 256;

  // staging geometry: 1024 16B-chunks per half-tile; thread covers c=tid,+512
  int rl[2], csw[2], ldo[2];
#pragma unroll
  for (int i = 0; i < 2; ++i) {
    int c = i * 512 + tid;
    rl[i] = c >> 3;
    csw[i] = (((c & 7) ^ (rl[i] & 7)) << 3);  // pre-swizzled col (rule #21)
    ldo[i] = (i * 512 + (wave << 6)) << 3;    // linear LDS dest (shorts)
  }
  const int NT = K >> 6;

  auto stA = [&](int t, int h, int d) {
#pragma unroll
    for (int i = 0; i < 2; ++i)
      glds16(A + (size_t)(bm + h * 128 + rl[i]) * K + t * 64 + csw[i], &As[d][h][ldo[i]]);
  };
  auto stB = [&](int t, int h, int d) {
#pragma unroll
    for (int i = 0; i < 2; ++i)
      glds16(BT + (size_t)(bn + h * 128 + rl[i]) * K + t * 64 + csw[i], &Bs[d][h][ldo[i]]);
  };

  // prologue: tile0 (4 halves -> dbuf0) + tile1.A.h0 -> dbuf1
  stA(0, 0, 0); stA(0, 1, 0); stB(0, 0, 0); stB(0, 1, 0);
  stA(1, 0, 1);
  asm volatile("s_waitcnt vmcnt(2)" ::: "memory");
  asm volatile("s_barrier" ::: "memory");

  f32x4 acc[8][4] = {};
  s16x8 af[4][2], bf0[2][2], bf1[2][2];
  const int brow = (wn & 1) * 64;
  const int U = NT >> 1;

  for (int u = 0; u < U; ++u) {
    const int t1 = 2 * u + 1;
    const int q0 = (2 * u + 2 < NT) ? 2 * u + 2 : 0;  // dummy-clamped (dead regions)
    const int q1 = (2 * u + 3 < NT) ? 2 * u + 3 : 0;
#pragma unroll
    for (int d = 0; d < 2; ++d) {
      const short* as = As[d][wm];
      const short* bsl = Bs[d][wn >> 1];
      // ---- phase 0/4: read af(m0-3)+bf0, MFMA quad(0,0) ----
#pragma unroll
      for (int m = 0; m < 4; ++m)
#pragma unroll
        for (int kk = 0; kk < 2; ++kk)
          af[m][kk] = *(const s16x8*)&as[(m * 16 + r) * 64 + (((kk * 4 + g) ^ (r & 7)) << 3)];
#pragma unroll
      for (int n = 0; n < 2; ++n)
#pragma unroll
        for (int kk = 0; kk < 2; ++kk)
          bf0[n][kk] = *(const s16x8*)&bsl[(brow + n * 16 + r) * 64 + (((kk * 4 + g) ^ (r & 7)) << 3)];
      if (d == 0) stA(t1, 1, 1); else stA(q0, 1, 0);
      asm volatile("s_waitcnt lgkmcnt(0)" ::: "memory");
      __builtin_amdgcn_sched_barrier(0);
      __builtin_amdgcn_s_setprio(1);
#pragma unroll
      for (int m = 0; m < 4; ++m)
#pragma unroll
        for (int n = 0; n < 2; ++n)
#pragma unroll
          for (int kk = 0; kk < 2; ++kk)
            acc[m][n] = __builtin_amdgcn_mfma_f32_16x16x32_bf16(af[m][kk], bf0[n][kk], acc[m][n], 0, 0, 0);
      __builtin_amdgcn_s_setprio(0);
      asm volatile("s_barrier" ::: "memory");
      // ---- phase 1/5: read bf1, MFMA quad(0,1) ----
#pragma unroll
      for (int n = 0; n < 2; ++n)
#pragma unroll
        for (int kk = 0; kk < 2; ++kk)
          bf1[n][kk] = *(const s16x8*)&bsl[(brow + (n + 2) * 16 + r) * 64 + (((kk * 4 + g) ^ (r & 7)) << 3)];
      if (d == 0) stB(t1, 0, 1); else stB(q0, 0, 0);
      asm volatile("s_waitcnt lgkmcnt(0)" ::: "memory");
      __builtin_amdgcn_sched_barrier(0);
      __builtin_amdgcn_s_setprio(1);
#pragma unroll
      for (int m = 0; m < 4; ++m)
#pragma unroll
        for (int n = 0; n < 2; ++n)
#pragma unroll
          for (int kk = 0; kk < 2; ++kk)
            acc[m][n + 2] = __builtin_amdgcn_mfma_f32_16x16x32_bf16(af[m][kk], bf1[n][kk], acc[m][n + 2], 0, 0, 0);
      __builtin_amdgcn_s_setprio(0);
      asm volatile("s_barrier" ::: "memory");
      // ---- phase 2/6: read af(m4-7), MFMA quad(1,1) ----
#pragma unroll
      for (int m = 0; m < 4; ++m)
#pragma unroll
        for (int kk = 0; kk < 2; ++kk)
          af[m][kk] = *(const s16x8*)&as[((m + 4) * 16 + r) * 64 + (((kk * 4 + g) ^ (r & 7)) << 3)];
      if (d == 0) stB(t1, 1, 1); else stB(q0, 1, 0);
      asm volatile("s_waitcnt lgkmcnt(0)" ::: "memory");
      __builtin_amdgcn_sched_barrier(0);
      __builtin_amdgcn_s_setprio(1);
#pragma unroll
      for (int m = 0; m < 4; ++m)
#pragma unroll
        for (int n = 0; n < 2; ++n)
#pragma unroll
          for (int kk = 0; kk < 2; ++kk)
            acc[m + 4][n + 2] = __builtin_amdgcn_mfma_f32_16x16x32_bf16(af[m][kk], bf1[n][kk], acc[m + 4][n + 2], 0, 0, 0);
      __builtin_amdgcn_s_setprio(0);
      asm volatile("s_barrier" ::: "memory");
      // ---- phase 3/7: no reads, MFMA quad(1,0), counted gate ----
      if (d == 0) stA(q0, 0, 0); else stA(q1, 0, 1);
      __builtin_amdgcn_s_setprio(1);
#pragma unroll
      for (int m = 0; m < 4; ++m)
#pragma unroll
        for (int n = 0; n < 2; ++n)
#pragma unroll
          for (int kk = 0; kk < 2; ++kk)
            acc[m + 4][n] = __builtin_amdgcn_mfma_f32_16x16x32_bf16(af[m][kk], bf0[n][kk], acc[m + 4][n], 0, 0, 0);
      __builtin_amdgcn_s_setprio(0);
      asm volatile("s_waitcnt vmcnt(2)" ::: "memory");
      asm volatile("s_barrier" ::: "memory");
    }
  }
  asm volatile("s_waitcnt vmcnt(0)" ::: "memory");  // drain dummy stagings

  // epilogue: C col=lane&15, row=(lane>>4)*4+j
#pragma unroll
  for (int m = 0; m < 8; ++m) {
    int row = bm + wm * 128 + m * 16 + g * 4;
#pragma unroll
    for (int n = 0; n < 4; ++n) {
      int col = bn + wn * 64 + n * 16 + r;
      if (col < N) {
#pragma unroll
        for (int j = 0; j < 4; ++j) {
          float v = acc[m][n][j];
          if (BIAS) v += bias[col];
          if (ACT) v = gelu_tanh(v);
          if (WF) Cf[(size_t)(row + j) * N + col] = v;
          if (WB) Cb[(size_t)(row + j) * N + col] = f2bf(v);
        }
      }
    }
  }
}

// ---------------- Flash attention (causal, GQA), bf16 in/out -------------
__global__ __launch_bounds__(256)
void attn_fwd(const short* __restrict__ qbuf, const short* __restrict__ kbuf,
              const short* __restrict__ vbuf, short* __restrict__ obuf) {
  __shared__ short Qs[64][136];
  __shared__ short Ks[32][136];
  __shared__ short Vt[128][40];   // [d][j ^ f(d)], f(d)=((d>>3)&3)<<3
  __shared__ short Ps[4][16][40];
  const int tid = threadIdx.x;
  int lin = blockIdx.x + blockIdx.y * gridDim.x;  // 32 x 16 grid
  int sw = (lin & 7) * 64 + (lin >> 3);
  const int qbase = (sw & 31) * 64;
  const int h = sw >> 5;
  const int kh = h >> 3;
  const int wave = tid >> 6;
  const int lane = tid & 63;
  const int g = lane >> 4;
  const int r = lane & 15;

#pragma unroll
  for (int i = 0; i < 4; ++i) {
    int idx = tid + i * 256;
    int row = idx >> 4;
    int c8 = (idx & 15) << 3;
    s16x8 v = *(const s16x8*)(qbuf + (size_t)(qbase + row) * DMODEL + h * DHEAD + c8);
    *(s16x8*)&Qs[row][c8] = v;
  }

  f32x4 O[8];
#pragma unroll
  for (int d = 0; d < 8; ++d) O[d] = (f32x4){0.f, 0.f, 0.f, 0.f};
  float mst[4], lst[4];
#pragma unroll
  for (int j = 0; j < 4; ++j) { mst[j] = -1e30f; lst[j] = 0.f; }
  const int nt = (qbase + 64) >> 5;
  const int qrow0 = qbase + wave * 16;

  for (int jt = 0; jt < nt; ++jt) {
    const int jb = jt * 32;
    __syncthreads();
#pragma unroll
    for (int i = 0; i < 2; ++i) {
      int idx = tid + i * 256;
      int row = idx >> 4;
      int c8 = (idx & 15) << 3;
      s16x8 kv = *(const s16x8*)(kbuf + (size_t)(jb + row) * (KVHEAD * DHEAD) + kh * DHEAD + c8);
      *(s16x8*)&Ks[row][c8] = kv;
      s16x8 vv = *(const s16x8*)(vbuf + (size_t)(jb + row) * (KVHEAD * DHEAD) + kh * DHEAD + c8);
#pragma unroll
      for (int u = 0; u < 8; ++u) {
        int d = c8 + u;
        Vt[d][row ^ (((d >> 3) & 3) << 3)] = vv[u];
      }
    }
    __syncthreads();

    f32x4 sc[2];
    sc[0] = (f32x4){0.f, 0.f, 0.f, 0.f};
    sc[1] = (f32x4){0.f, 0.f, 0.f, 0.f};
    __builtin_amdgcn_s_setprio(1);
#pragma unroll
    for (int n = 0; n < 2; ++n)
#pragma unroll
      for (int kc = 0; kc < 4; ++kc) {
        s16x8 a = *(const s16x8*)&Qs[wave * 16 + r][kc * 32 + g * 8];
        s16x8 bb = *(const s16x8*)&Ks[n * 16 + r][kc * 32 + g * 8];
        sc[n] = __builtin_amdgcn_mfma_f32_16x16x32_bf16(a, bb, sc[n], 0, 0, 0);
      }
    __builtin_amdgcn_s_setprio(0);
    const float scale = 0.08838834764831845f;
    float pmax[4];
#pragma unroll
    for (int j = 0; j < 4; ++j) {
      int irow = qrow0 + g * 4 + j;
#pragma unroll
      for (int n = 0; n < 2; ++n) {
        int jcol = jb + n * 16 + r;
        sc[n][j] = (jcol <= irow) ? sc[n][j] * scale : -1e30f;
      }
      pmax[j] = fmaxf(sc[0][j], sc[1][j]);
    }
#pragma unroll
    for (int off = 1; off < 16; off <<= 1)
#pragma unroll
      for (int j = 0; j < 4; ++j) pmax[j] = fmaxf(pmax[j], __shfl_xor(pmax[j], off));

    float alpha[4], rsum[4];
#pragma unroll
    for (int j = 0; j < 4; ++j) {
      float mnew = fmaxf(mst[j], pmax[j]);
      alpha[j] = __expf(mst[j] - mnew);
      mst[j] = mnew;
      sc[0][j] = __expf(sc[0][j] - mnew);
      sc[1][j] = __expf(sc[1][j] - mnew);
      rsum[j] = sc[0][j] + sc[1][j];
    }
#pragma unroll
    for (int off = 1; off < 16; off <<= 1)
#pragma unroll
      for (int j = 0; j < 4; ++j) rsum[j] += __shfl_xor(rsum[j], off);
#pragma unroll
    for (int j = 0; j < 4; ++j) lst[j] = lst[j] * alpha[j] + rsum[j];
#pragma unroll
    for (int d = 0; d < 8; ++d)
#pragma unroll
      for (int j = 0; j < 4; ++j) O[d][j] *= alpha[j];
#pragma unroll
    for (int j = 0; j < 4; ++j) {
      Ps[wave][g * 4 + j][r] = f2bf(sc[0][j]);
      Ps[wave][g * 4 + j][16 + r] = f2bf(sc[1][j]);
    }
    s16x8 a = *(const s16x8*)&Ps[wave][r][g * 8];
    __builtin_amdgcn_s_setprio(1);
#pragma unroll
    for (int d = 0; d < 8; ++d) {
      int dd = d * 16 + r;
      s16x8 bb = *(const s16x8*)&Vt[dd][(g << 3) ^ (((dd >> 3) & 3) << 3)];
      O[d] = __builtin_amdgcn_mfma_f32_16x16x32_bf16(a, bb, O[d], 0, 0, 0);
    }
    __builtin_amdgcn_s_setprio(0);
  }
  float linv[4];
#pragma unroll
  for (int j = 0; j < 4; ++j) linv[j] = 1.f / lst[j];
#pragma unroll
  for (int d = 0; d < 8; ++d)
#pragma unroll
    for (int j = 0; j < 4; ++j)
      obuf[(size_t)(qrow0 + g * 4 + j) * DMODEL + h * DHEAD + d * 16 + r] =
          f2bf(O[d][j] * linv[j]);
}

// ---------------- host side ----------------
extern "C" void kernel_launch(void* const* d_in, const int* in_sizes, int n_in,
                              void* d_out, int out_size, void* d_ws, size_t ws_size,
                              hipStream_t stream) {
  const int* text = (const int*)d_in[0];
  const float* embed_w = (const float*)d_in[1];
  const float* model_g = (const float*)d_in[2];
  const float* model_b = (const float*)d_in[3];
  const float* blk_g = (const float*)d_in[4];
  const float* blk_b = (const float*)d_in[5];
  const float* attn_g = (const float*)d_in[6];
  const float* attn_b = (const float*)d_in[7];
  const float* wq = (const float*)d_in[8];
  const float* wk = (const float*)d_in[9];
  const float* wv = (const float*)d_in[10];
  const float* wo = (const float*)d_in[11];
  const float* qn_g = (const float*)d_in[12];
  const float* kn_g = (const float*)d_in[13];
  const float* w1 = (const float*)d_in[14];
  const float* b1 = (const float*)d_in[15];
  const float* w2 = (const float*)d_in[16];
  const float* b2 = (const float*)d_in[17];
  const float* head_g = (const float*)d_in[18];
  const float* head_b = (const float*)d_in[19];
  const float* head_w = (const float*)d_in[20];
  const float* head_bias = (const float*)d_in[21];
  float* out = (float*)d_out;

  const size_t SD = (size_t)S_LEN * DMODEL;
  const size_t SKV = (size_t)S_LEN * KVHEAD * DHEAD;
  const size_t SI = (size_t)S_LEN * INNER_DIM;
  const size_t WD = (size_t)DMODEL * DMODEL;
  const size_t WKV = (size_t)DMODEL * KVHEAD * DHEAD;
  const size_t WI = (size_t)DMODEL * INNER_DIM;

  char* p = (char*)d_ws;
  float* xres  = (float*)p; p += SD * 4;
  float* hb    = (float*)p; p += SD * 4;
  float* h2    = (float*)p; p += SD * 4;
  float* qkvf  = (float*)p; p += (size_t)S_LEN * QKVN * 4;
  short* hn16  = (short*)p; p += SD * 2;
  short* h216  = (short*)p; p += SD * 2;
  short* ao16  = (short*)p; p += SD * 2;
  short* ffi16 = (short*)p; p += SI * 2;
  short* qb16  = (short*)p; p += SD * 2;
  short* kb16  = (short*)p; p += SKV * 2;
  short* vb16  = (short*)p; p += SKV * 2;
  short* wqkvT = (short*)p; p += (size_t)QKVN * DMODEL * 2;
  short* woT   = (short*)p; p += WD * 2;
  short* w1T   = (short*)p; p += WI * 2;
  short* w2T   = (short*)p; p += WI * 2;
  short* headT = w1T;  // reused after layers (10240*2048*2 = 42MB < 64MB)

  dim3 blk(256);
  embed_gather<<<S_LEN, blk, 0, stream>>>(text, embed_w, xres);

  for (int i = 0; i < NLAYER; ++i) {
    const float* wq_i = wq + (size_t)i * WD;
    const float* wk_i = wk + (size_t)i * WKV;
    const float* wv_i = wv + (size_t)i * WKV;
    const float* wo_i = wo + (size_t)i * WD;
    const float* w1_i = w1 + (size_t)i * WI;
    const float* b1_i = b1 + (size_t)i * INNER_DIM;
    const float* w2_i = w2 + (size_t)i * WI;
    const float* b2_i = b2 + (size_t)i * DMODEL;

    wtrans64<<<dim3(32, 32), blk, 0, stream>>>(wq_i, wqkvT, DMODEL, DMODEL, DMODEL);
    wtrans64<<<dim3(4, 32), blk, 0, stream>>>(wk_i, wqkvT + (size_t)2048 * DMODEL, DMODEL, 256, 256);
    wtrans64<<<dim3(4, 32), blk, 0, stream>>>(wv_i, wqkvT + (size_t)2304 * DMODEL, DMODEL, 256, 256);
    wtrans64<<<dim3(32, 32), blk, 0, stream>>>(wo_i, woT, DMODEL, DMODEL, DMODEL);
    wtrans64<<<dim3(128, 32), blk, 0, stream>>>(w1_i, w1T, DMODEL, INNER_DIM, INNER_DIM);
    wtrans64<<<dim3(32, 128), blk, 0, stream>>>(w2_i, w2T, INNER_DIM, DMODEL, DMODEL);

    ln_triple<<<S_LEN, blk, 0, stream>>>(xres, model_g, model_b,
                                         blk_g + i * DMODEL, blk_b + i * DMODEL,
                                         attn_g + i * DMODEL, attn_b + i * DMODEL,
                                         hb, hn16);

    gemm_db<128, 128, 64, 2, 2, 0, false, false, true, false>
        <<<dim3(QKVN / 128, S_LEN / 128), dim3(256), 0, stream>>>(
        hn16, wqkvT, nullptr, nullptr, qkvf, nullptr, S_LEN, QKVN, DMODEL);

    qknorm_s<NHEAD><<<(S_LEN * NHEAD) / 4, blk, 0, stream>>>(
        qkvf, 0, qn_g + i * DHEAD, qb16, S_LEN * NHEAD);
    qknorm_s<KVHEAD><<<(S_LEN * KVHEAD) / 4, blk, 0, stream>>>(
        qkvf, 2048, kn_g + i * DHEAD, kb16, S_LEN * KVHEAD);
    vconv<<<(S_LEN * 64) / 256, blk, 0, stream>>>(qkvf, vb16);

    attn_fwd<<<dim3(S_LEN / 64, NHEAD), blk, 0, stream>>>(qb16, kb16, vb16, ao16);

    gemm_db<128, 128, 64, 2, 2, 0, false, true, true, true>
        <<<dim3(DMODEL / 128, S_LEN / 128), dim3(256), 0, stream>>>(
        ao16, woT, nullptr, hb, h2, h216, S_LEN, DMODEL, DMODEL);
    // ffi = gelu(h2 @ w1 + b1): 8-phase 256^2 (256 blocks = 1/CU)
    gemm_8ph<1, true, false, true>
        <<<dim3(INNER_DIM / 256, S_LEN / 256), dim3(512), 0, stream>>>(
        h216, w1T, b1_i, nullptr, ffi16, S_LEN, INNER_DIM, DMODEL);
    gemm_db<128, 128, 64, 2, 2, 0, true, true, true, false>
        <<<dim3(DMODEL / 128, S_LEN / 128), dim3(256), 0, stream>>>(
        ffi16, w2T, b2_i, h2, xres, nullptr, S_LEN, DMODEL, INNER_DIM);
  }

  wtrans64<<<dim3(VOCAB_PAD / 64, 32), blk, 0, stream>>>(head_w, headT, DMODEL, VOCAB, VOCAB_PAD);
  ln_dual<<<S_LEN, blk, 0, stream>>>(xres, model_g, model_b, head_g, head_b, hn16);
  // head: 8-phase 256^2 (320 blocks)
  gemm_8ph<0, true, true, false>
      <<<dim3(VOCAB_PAD / 256, S_LEN / 256), dim3(512), 0, stream>>>(
      hn16, headT, head_bias, out, nullptr, S_LEN, VOCAB, DMODEL);
}

// Round 6
// 1901.268 us; speedup vs baseline: 1.1944x; 1.1498x over previous
//
#include <hip/hip_runtime.h>
#include <math.h>

#define S_LEN 2048
#define DMODEL 2048
#define NHEAD 16
#define KVHEAD 2
#define DHEAD 128
#define NLAYER 4
#define VOCAB 10000
#define INNER_DIM 8192
#define LN_EPS 1e-5f
#define VOCAB_PAD 10240  // 40*256
#define QKVN 2560        // 2048 q + 256 k + 256 v

typedef __attribute__((ext_vector_type(4))) float f32x4;
typedef __attribute__((ext_vector_type(2))) float f32x2;
typedef __attribute__((ext_vector_type(8))) short s16x8;
typedef __attribute__((ext_vector_type(4))) short s16x4;

__device__ __forceinline__ short f2bf(float f) {
  union { float f; unsigned u; } v; v.f = f;
  unsigned r = v.u + 0x7FFFu + ((v.u >> 16) & 1u);  // RNE
  return (short)(r >> 16);
}

__device__ __forceinline__ float gelu_tanh(float x) {
  float x3 = x * x * x;
  return 0.5f * x * (1.0f + tanhf(0.7978845608028654f * (x + 0.044715f * x3)));
}

__device__ __forceinline__ void glds16(const void* g, void* l) {
  __builtin_amdgcn_global_load_lds(
      (const __attribute__((address_space(1))) unsigned int*)g,
      (__attribute__((address_space(3))) unsigned int*)l, 16, 0, 0);
}

// ---------------- weight transpose 64x64 tiles: W[K][N] -> WT[NP][K] bf16 --
__global__ __launch_bounds__(256)
void wtrans64(const float* __restrict__ W, short* __restrict__ WT,
              int K, int N, int NP) {
  __shared__ float ld[64][65];
  const int n0 = blockIdx.x * 64, k0 = blockIdx.y * 64;
  const int tid = threadIdx.x;
  const int rbase = tid >> 4;
  const int c4 = (tid & 15) * 4;
#pragma unroll
  for (int q = 0; q < 4; ++q) {
    int kk = rbase + q * 16;
    const float* wp = W + (size_t)(k0 + kk) * N + n0 + c4;
    float v0, v1, v2, v3;
    if (n0 + c4 + 3 < N) {
      f32x4 v = *(const f32x4*)wp;
      v0 = v[0]; v1 = v[1]; v2 = v[2]; v3 = v[3];
    } else {
      v0 = (n0 + c4 + 0 < N) ? wp[0] : 0.f;
      v1 = (n0 + c4 + 1 < N) ? wp[1] : 0.f;
      v2 = (n0 + c4 + 2 < N) ? wp[2] : 0.f;
      v3 = (n0 + c4 + 3 < N) ? wp[3] : 0.f;
    }
    ld[kk][c4 + 0] = v0; ld[kk][c4 + 1] = v1;
    ld[kk][c4 + 2] = v2; ld[kk][c4 + 3] = v3;
  }
  __syncthreads();
#pragma unroll
  for (int s = 0; s < 2; ++s) {
    int lin = tid + s * 256;
    int nn = lin >> 3;
    int ks = lin & 7;
    int n = n0 + nn;
    if (n < NP) {
      s16x8 o;
#pragma unroll
      for (int j = 0; j < 8; ++j)
        o[j] = (n < N) ? f2bf(ld[ks * 8 + j][nn]) : (short)0;
      *(s16x8*)&WT[(size_t)n * K + k0 + ks * 8] = o;
    }
  }
}

// ---------------- V transpose: qkvf v-slice [S][256] (stride QKVN) -> vt[256][S]
__global__ __launch_bounds__(256)
void vtrans(const float* __restrict__ qkvf, short* __restrict__ vt) {
  __shared__ float ld[64][65];
  const int n0 = blockIdx.x * 64, k0 = blockIdx.y * 64;  // n=d (256), k=s (2048)
  const int tid = threadIdx.x;
  const int rbase = tid >> 4;
  const int c4 = (tid & 15) * 4;
#pragma unroll
  for (int q = 0; q < 4; ++q) {
    int kk = rbase + q * 16;
    f32x4 v = *(const f32x4*)(qkvf + (size_t)(k0 + kk) * QKVN + 2304 + n0 + c4);
    ld[kk][c4 + 0] = v[0]; ld[kk][c4 + 1] = v[1];
    ld[kk][c4 + 2] = v[2]; ld[kk][c4 + 3] = v[3];
  }
  __syncthreads();
#pragma unroll
  for (int s = 0; s < 2; ++s) {
    int lin = tid + s * 256;
    int nn = lin >> 3;
    int ks = lin & 7;
    s16x8 o;
#pragma unroll
    for (int j = 0; j < 8; ++j) o[j] = f2bf(ld[ks * 8 + j][nn]);
    *(s16x8*)&vt[(size_t)(n0 + nn) * S_LEN + k0 + ks * 8] = o;
  }
}

// ---------------- embedding gather ----------------
__global__ __launch_bounds__(256)
void embed_gather(const int* __restrict__ text, const float* __restrict__ ew,
                  float* __restrict__ out) {
  const int row = blockIdx.x;
  const int tok = text[row];
  const float* src = ew + (size_t)tok * DMODEL;
  float* dst = out + (size_t)row * DMODEL;
#pragma unroll
  for (int i = 0; i < 2; ++i) {
    int idx = (threadIdx.x + i * 256) * 4;
    *(f32x4*)(dst + idx) = *(const f32x4*)(src + idx);
  }
}

// ---------------- triple LayerNorm: model -> block -> attn ----------------
__global__ __launch_bounds__(256)
void ln_triple(const float* __restrict__ in,
               const float* __restrict__ mg, const float* __restrict__ mb,
               const float* __restrict__ bg, const float* __restrict__ bb,
               const float* __restrict__ ag, const float* __restrict__ ab,
               float* __restrict__ hb, short* __restrict__ hn16) {
  const int row = blockIdx.x;
  const int tid = threadIdx.x;
  const int wave = tid >> 6;
  __shared__ float rs[3][4], rs2[3][4];
  float v[8];
  const float* x = in + (size_t)row * DMODEL;
#pragma unroll
  for (int i = 0; i < 8; ++i) v[i] = x[tid + i * 256];
#pragma unroll
  for (int rnd = 0; rnd < 3; ++rnd) {
    float s = 0.f, s2 = 0.f;
#pragma unroll
    for (int i = 0; i < 8; ++i) { s += v[i]; s2 += v[i] * v[i]; }
#pragma unroll
    for (int off = 1; off < 64; off <<= 1) {
      s += __shfl_xor(s, off); s2 += __shfl_xor(s2, off);
    }
    if ((tid & 63) == 0) { rs[rnd][wave] = s; rs2[rnd][wave] = s2; }
    __syncthreads();
    s = rs[rnd][0] + rs[rnd][1] + rs[rnd][2] + rs[rnd][3];
    s2 = rs2[rnd][0] + rs2[rnd][1] + rs2[rnd][2] + rs2[rnd][3];
    const float mean = s * (1.f / DMODEL);
    const float var = s2 * (1.f / DMODEL) - mean * mean;
    const float rstd = rsqrtf(var + LN_EPS);
    const float* gg = (rnd == 0) ? mg : (rnd == 1) ? bg : ag;
    const float* bbv = (rnd == 0) ? mb : (rnd == 1) ? bb : ab;
#pragma unroll
    for (int i = 0; i < 8; ++i) {
      int idx = tid + i * 256;
      v[i] = (v[i] - mean) * rstd * gg[idx] + bbv[idx];
    }
    if (rnd == 1) {
      float* o = hb + (size_t)row * DMODEL;
#pragma unroll
      for (int i = 0; i < 8; ++i) o[tid + i * 256] = v[i];
    }
  }
  short* o = hn16 + (size_t)row * DMODEL;
#pragma unroll
  for (int i = 0; i < 8; ++i) o[tid + i * 256] = f2bf(v[i]);
}

// ---------------- dual LN (model -> head), bf16 out ----------------
__global__ __launch_bounds__(256)
void ln_dual(const float* __restrict__ in,
             const float* __restrict__ mg, const float* __restrict__ mb,
             const float* __restrict__ hg, const float* __restrict__ hbv,
             short* __restrict__ out16) {
  const int row = blockIdx.x;
  const int tid = threadIdx.x;
  const int wave = tid >> 6;
  __shared__ float rs[2][4], rs2[2][4];
  float v[8];
  const float* x = in + (size_t)row * DMODEL;
#pragma unroll
  for (int i = 0; i < 8; ++i) v[i] = x[tid + i * 256];
#pragma unroll
  for (int rnd = 0; rnd < 2; ++rnd) {
    float s = 0.f, s2 = 0.f;
#pragma unroll
    for (int i = 0; i < 8; ++i) { s += v[i]; s2 += v[i] * v[i]; }
#pragma unroll
    for (int off = 1; off < 64; off <<= 1) {
      s += __shfl_xor(s, off); s2 += __shfl_xor(s2, off);
    }
    if ((tid & 63) == 0) { rs[rnd][wave] = s; rs2[rnd][wave] = s2; }
    __syncthreads();
    s = rs[rnd][0] + rs[rnd][1] + rs[rnd][2] + rs[rnd][3];
    s2 = rs2[rnd][0] + rs2[rnd][1] + rs2[rnd][2] + rs2[rnd][3];
    const float mean = s * (1.f / DMODEL);
    const float var = s2 * (1.f / DMODEL) - mean * mean;
    const float rstd = rsqrtf(var + LN_EPS);
    const float* gg = (rnd == 0) ? mg : hg;
    const float* bbv = (rnd == 0) ? mb : hbv;
#pragma unroll
    for (int i = 0; i < 8; ++i) {
      int idx = tid + i * 256;
      v[i] = (v[i] - mean) * rstd * gg[idx] + bbv[idx];
    }
  }
  short* o = out16 + (size_t)row * DMODEL;
#pragma unroll
  for (int i = 0; i < 8; ++i) o[tid + i * 256] = f2bf(v[i]);
}

// ---------------- fused q+k head-norm (S*18 row jobs, 1 row/wave) --------
__global__ __launch_bounds__(256)
void normqk(const float* __restrict__ qkvf,
            const float* __restrict__ qg, const float* __restrict__ kg,
            short* __restrict__ qb16, short* __restrict__ kb16) {
  const int rowjob = blockIdx.x * 4 + (threadIdx.x >> 6);
  const int lane = threadIdx.x & 63;
  const int s = rowjob / 18, sub = rowjob - s * 18;
  const float* p; short* o; const float* g;
  if (sub < 16) {
    p = qkvf + (size_t)s * QKVN + sub * DHEAD;
    o = qb16 + ((size_t)s * 16 + sub) * DHEAD;
    g = qg;
  } else {
    p = qkvf + (size_t)s * QKVN + 2048 + (sub - 16) * DHEAD;
    o = kb16 + ((size_t)s * 2 + (sub - 16)) * DHEAD;
    g = kg;
  }
  f32x2 t = *(const f32x2*)(p + lane * 2);
  float sm = t[0] + t[1];
  float s2 = t[0] * t[0] + t[1] * t[1];
#pragma unroll
  for (int off = 1; off < 64; off <<= 1) {
    sm += __shfl_xor(sm, off); s2 += __shfl_xor(s2, off);
  }
  const float mean = sm * (1.f / DHEAD);
  const float var = s2 * (1.f / DHEAD) - mean * mean;
  const float rstd = rsqrtf(var + LN_EPS);
  o[lane * 2] = f2bf((t[0] - mean) * rstd * g[lane * 2]);
  o[lane * 2 + 1] = f2bf((t[1] - mean) * rstd * g[lane * 2 + 1]);
}

// ---------------- 2-phase double-buffered bf16 GEMM (R3, proven) ---------
template<int BM, int BN, int BK, int WM, int WN, int ACT, bool BIAS, bool RES,
         bool WF, bool WB>
__global__ __launch_bounds__(WM * WN * 64)
void gemm_db(const short* __restrict__ A, const short* __restrict__ BT,
             const float* __restrict__ bias, const float* __restrict__ res,
             float* __restrict__ Cf, short* __restrict__ Cb,
             int M, int N, int K) {
  constexpr int THREADS = WM * WN * 64;
  constexpr int MR = BM / WM / 16;
  constexpr int NR = BN / WN / 16;
  constexpr int KH = BK / 32;
  constexpr int SLOTS = BK / 8;
  constexpr int SMASK = SLOTS - 1;
  constexpr int RSH = (SLOTS == 8) ? 0 : 1;
  constexpr int CSH = (SLOTS == 8) ? 3 : 2;
  constexpr int NI = (BM * BK) / (THREADS * 8);
  __shared__ short As[2][BM * BK];
  __shared__ short Bs[2][BN * BK];
  const int tid = threadIdx.x;
  const int wave = tid >> 6, lane = tid & 63;
  const int g = lane >> 4, r = lane & 15;
  const int wm = wave / WN, wn = wave % WN;

  const int GY = gridDim.y;
  int lin = blockIdx.x + blockIdx.y * gridDim.x;
  int nwg = gridDim.x * GY;
  int sw = ((nwg & 7) == 0) ? ((lin & 7) * (nwg >> 3) + (lin >> 3)) : lin;
  const int bm = (sw % GY) * BM;
  const int bn = (sw / GY) * BN;

  const short* gsrc[2 * NI];
  short* ldst[2][2 * NI];
#pragma unroll
  for (int i = 0; i < NI; ++i) {
    int c = i * THREADS + tid;
    int row = c >> CSH;
    int slot = c & SMASK;
    int col = ((slot ^ ((row >> RSH) & SMASK)) << 3);
    gsrc[i] = A + (size_t)(bm + row) * K + col;
    gsrc[NI + i] = BT + (size_t)(bn + row) * K + col;
    int base = (i * THREADS + (wave << 6)) << 3;
    ldst[0][i] = &As[0][base]; ldst[0][NI + i] = &Bs[0][base];
    ldst[1][i] = &As[1][base]; ldst[1][NI + i] = &Bs[1][base];
  }

  f32x4 acc[MR][NR] = {};
  const int NT = K / BK;

#pragma unroll
  for (int i = 0; i < 2 * NI; ++i) glds16(gsrc[i], ldst[0][i]);
  asm volatile("s_waitcnt vmcnt(0)" ::: "memory");
  __syncthreads();

  for (int t = 0; t < NT; ++t) {
    const int cur = t & 1;
    const short* as = As[cur];
    const short* bs = Bs[cur];
    s16x8 bfr[NR][KH], af[MR / 2][KH];
#pragma unroll
    for (int n = 0; n < NR; ++n) {
      int rr = wn * (NR * 16) + n * 16 + r;
#pragma unroll
      for (int kk = 0; kk < KH; ++kk) {
        int lg = kk * 4 + g;
        bfr[n][kk] = *(const s16x8*)&bs[rr * BK + ((lg ^ ((rr >> RSH) & SMASK)) << 3)];
      }
    }
#pragma unroll
    for (int mm = 0; mm < MR / 2; ++mm) {
      int rr = wm * (MR * 16) + mm * 16 + r;
#pragma unroll
      for (int kk = 0; kk < KH; ++kk) {
        int lg = kk * 4 + g;
        af[mm][kk] = *(const s16x8*)&as[rr * BK + ((lg ^ ((rr >> RSH) & SMASK)) << 3)];
      }
    }
    if (t + 1 < NT) {
#pragma unroll
      for (int i = 0; i < 2 * NI; ++i) glds16(gsrc[i] + (t + 1) * BK, ldst[cur ^ 1][i]);
    }
    asm volatile("s_waitcnt lgkmcnt(0)" ::: "memory");
    __builtin_amdgcn_sched_barrier(0);
    __builtin_amdgcn_s_setprio(1);
#pragma unroll
    for (int mm = 0; mm < MR / 2; ++mm)
#pragma unroll
      for (int n = 0; n < NR; ++n)
#pragma unroll
        for (int kk = 0; kk < KH; ++kk)
          acc[mm][n] = __builtin_amdgcn_mfma_f32_16x16x32_bf16(af[mm][kk], bfr[n][kk], acc[mm][n], 0, 0, 0);
    __builtin_amdgcn_s_setprio(0);
    __builtin_amdgcn_s_barrier();
#pragma unroll
    for (int mm = 0; mm < MR / 2; ++mm) {
      int rr = wm * (MR * 16) + (MR / 2 + mm) * 16 + r;
#pragma unroll
      for (int kk = 0; kk < KH; ++kk) {
        int lg = kk * 4 + g;
        af[mm][kk] = *(const s16x8*)&as[rr * BK + ((lg ^ ((rr >> RSH) & SMASK)) << 3)];
      }
    }
    asm volatile("s_waitcnt lgkmcnt(0)" ::: "memory");
    __builtin_amdgcn_sched_barrier(0);
    __builtin_amdgcn_s_setprio(1);
#pragma unroll
    for (int mm = 0; mm < MR / 2; ++mm)
#pragma unroll
      for (int n = 0; n < NR; ++n)
#pragma unroll
        for (int kk = 0; kk < KH; ++kk)
          acc[MR / 2 + mm][n] = __builtin_amdgcn_mfma_f32_16x16x32_bf16(af[mm][kk], bfr[n][kk], acc[MR / 2 + mm][n], 0, 0, 0);
    __builtin_amdgcn_s_setprio(0);
    __syncthreads();
  }

#pragma unroll
  for (int m = 0; m < MR; ++m) {
    int row = bm + wm * (MR * 16) + m * 16 + g * 4;
#pragma unroll
    for (int n = 0; n < NR; ++n) {
      int col = bn + wn * (NR * 16) + n * 16 + r;
      if (col < N) {
#pragma unroll
        for (int j = 0; j < 4; ++j) {
          float v = acc[m][n][j];
          if (BIAS) v += bias[col];
          if (ACT) v = gelu_tanh(v);
          if (RES) v += res[(size_t)(row + j) * N + col];
          if (WF) Cf[(size_t)(row + j) * N + col] = v;
          if (WB) Cb[(size_t)(row + j) * N + col] = f2bf(v);
        }
      }
    }
  }
}

// ---------------- 8-phase 256x256 bf16 GEMM ------------------------------
template<int ACT, bool BIAS, bool WF, bool WB>
__global__ __launch_bounds__(512, 2)
void gemm_8ph(const short* __restrict__ A, const short* __restrict__ BT,
              const float* __restrict__ bias,
              float* __restrict__ Cf, short* __restrict__ Cb,
              int M, int N, int K) {
  __shared__ short As[2][2][128 * 64];
  __shared__ short Bs[2][2][128 * 64];
  const int tid = threadIdx.x;
  const int wave = tid >> 6, lane = tid & 63;
  const int g = lane >> 4, r = lane & 15;
  const int wm = wave >> 2, wn = wave & 3;

  const int GY = gridDim.y;
  int lin = blockIdx.x + blockIdx.y * gridDim.x;
  int nwg = gridDim.x * GY;
  int sw = (lin & 7) * (nwg >> 3) + (lin >> 3);
  const int bm = (sw % GY) * 256;
  const int bn = (sw / GY) * 256;

  int rl[2], csw[2], ldo[2];
#pragma unroll
  for (int i = 0; i < 2; ++i) {
    int c = i * 512 + tid;
    rl[i] = c >> 3;
    csw[i] = (((c & 7) ^ (rl[i] & 7)) << 3);
    ldo[i] = (i * 512 + (wave << 6)) << 3;
  }
  const int NT = K >> 6;

  auto stA = [&](int t, int h, int d) {
#pragma unroll
    for (int i = 0; i < 2; ++i)
      glds16(A + (size_t)(bm + h * 128 + rl[i]) * K + t * 64 + csw[i], &As[d][h][ldo[i]]);
  };
  auto stB = [&](int t, int h, int d) {
#pragma unroll
    for (int i = 0; i < 2; ++i)
      glds16(BT + (size_t)(bn + h * 128 + rl[i]) * K + t * 64 + csw[i], &Bs[d][h][ldo[i]]);
  };

  stA(0, 0, 0); stA(0, 1, 0); stB(0, 0, 0); stB(0, 1, 0);
  stA(1, 0, 1);
  asm volatile("s_waitcnt vmcnt(2)" ::: "memory");
  asm volatile("s_barrier" ::: "memory");

  f32x4 acc[8][4] = {};
  s16x8 af[4][2], bf0[2][2], bf1[2][2];
  const int brow = (wn & 1) * 64;
  const int U = NT >> 1;

  for (int u = 0; u < U; ++u) {
    const int t1 = 2 * u + 1;
    const int q0 = (2 * u + 2 < NT) ? 2 * u + 2 : 0;
    const int q1 = (2 * u + 3 < NT) ? 2 * u + 3 : 0;
#pragma unroll
    for (int d = 0; d < 2; ++d) {
      const short* as = As[d][wm];
      const short* bsl = Bs[d][wn >> 1];
#pragma unroll
      for (int m = 0; m < 4; ++m)
#pragma unroll
        for (int kk = 0; kk < 2; ++kk)
          af[m][kk] = *(const s16x8*)&as[(m * 16 + r) * 64 + (((kk * 4 + g) ^ (r & 7)) << 3)];
#pragma unroll
      for (int n = 0; n < 2; ++n)
#pragma unroll
        for (int kk = 0; kk < 2; ++kk)
          bf0[n][kk] = *(const s16x8*)&bsl[(brow + n * 16 + r) * 64 + (((kk * 4 + g) ^ (r & 7)) << 3)];
      if (d == 0) stA(t1, 1, 1); else stA(q0, 1, 0);
      asm volatile("s_waitcnt lgkmcnt(0)" ::: "memory");
      __builtin_amdgcn_sched_barrier(0);
      __builtin_amdgcn_s_setprio(1);
#pragma unroll
      for (int m = 0; m < 4; ++m)
#pragma unroll
        for (int n = 0; n < 2; ++n)
#pragma unroll
          for (int kk = 0; kk < 2; ++kk)
            acc[m][n] = __builtin_amdgcn_mfma_f32_16x16x32_bf16(af[m][kk], bf0[n][kk], acc[m][n], 0, 0, 0);
      __builtin_amdgcn_s_setprio(0);
      asm volatile("s_barrier" ::: "memory");
#pragma unroll
      for (int n = 0; n < 2; ++n)
#pragma unroll
        for (int kk = 0; kk < 2; ++kk)
          bf1[n][kk] = *(const s16x8*)&bsl[(brow + (n + 2) * 16 + r) * 64 + (((kk * 4 + g) ^ (r & 7)) << 3)];
      if (d == 0) stB(t1, 0, 1); else stB(q0, 0, 0);
      asm volatile("s_waitcnt lgkmcnt(0)" ::: "memory");
      __builtin_amdgcn_sched_barrier(0);
      __builtin_amdgcn_s_setprio(1);
#pragma unroll
      for (int m = 0; m < 4; ++m)
#pragma unroll
        for (int n = 0; n < 2; ++n)
#pragma unroll
          for (int kk = 0; kk < 2; ++kk)
            acc[m][n + 2] = __builtin_amdgcn_mfma_f32_16x16x32_bf16(af[m][kk], bf1[n][kk], acc[m][n + 2], 0, 0, 0);
      __builtin_amdgcn_s_setprio(0);
      asm volatile("s_barrier" ::: "memory");
#pragma unroll
      for (int m = 0; m < 4; ++m)
#pragma unroll
        for (int kk = 0; kk < 2; ++kk)
          af[m][kk] = *(const s16x8*)&as[((m + 4) * 16 + r) * 64 + (((kk * 4 + g) ^ (r & 7)) << 3)];
      if (d == 0) stB(t1, 1, 1); else stB(q0, 1, 0);
      asm volatile("s_waitcnt lgkmcnt(0)" ::: "memory");
      __builtin_amdgcn_sched_barrier(0);
      __builtin_amdgcn_s_setprio(1);
#pragma unroll
      for (int m = 0; m < 4; ++m)
#pragma unroll
        for (int n = 0; n < 2; ++n)
#pragma unroll
          for (int kk = 0; kk < 2; ++kk)
            acc[m + 4][n + 2] = __builtin_amdgcn_mfma_f32_16x16x32_bf16(af[m][kk], bf1[n][kk], acc[m + 4][n + 2], 0, 0, 0);
      __builtin_amdgcn_s_setprio(0);
      asm volatile("s_barrier" ::: "memory");
      if (d == 0) stA(q0, 0, 0); else stA(q1, 0, 1);
      __builtin_amdgcn_s_setprio(1);
#pragma unroll
      for (int m = 0; m < 4; ++m)
#pragma unroll
        for (int n = 0; n < 2; ++n)
#pragma unroll
          for (int kk = 0; kk < 2; ++kk)
            acc[m + 4][n] = __builtin_amdgcn_mfma_f32_16x16x32_bf16(af[m][kk], bf0[n][kk], acc[m + 4][n], 0, 0, 0);
      __builtin_amdgcn_s_setprio(0);
      asm volatile("s_waitcnt vmcnt(2)" ::: "memory");
      asm volatile("s_barrier" ::: "memory");
    }
  }
  asm volatile("s_waitcnt vmcnt(0)" ::: "memory");

#pragma unroll
  for (int m = 0; m < 8; ++m) {
    int row = bm + wm * 128 + m * 16 + g * 4;
#pragma unroll
    for (int n = 0; n < 4; ++n) {
      int col = bn + wn * 64 + n * 16 + r;
      if (col < N) {
#pragma unroll
        for (int j = 0; j < 4; ++j) {
          float v = acc[m][n][j];
          if (BIAS) v += bias[col];
          if (ACT) v = gelu_tanh(v);
          if (WF) Cf[(size_t)(row + j) * N + col] = v;
          if (WB) Cb[(size_t)(row + j) * N + col] = f2bf(v);
        }
      }
    }
  }
}

// ---------------- Flash attention v2: causal-pair-balanced, KVBLK=64 -----
// grid (16,16): 256 blocks; block processes q-tiles {pair, 31-pair} of head h.
// All staging via global_load_lds with pre-swizzled sources. V pre-transposed.
__global__ __launch_bounds__(256)
void attn_fwd2(const short* __restrict__ qbuf, const short* __restrict__ kbuf,
               const short* __restrict__ vtb, short* __restrict__ obuf) {
  __shared__ short Qs[64 * 128];
  __shared__ short Ks[64 * 128];
  __shared__ short Vt[128 * 64];   // V^T tile, swizzled slots
  __shared__ short Ps[4][16][88];  // per-wave P, 88-pad => ~2-way banks
  const int tid = threadIdx.x;
  int lin = blockIdx.x + blockIdx.y * gridDim.x;
  int sw = (lin & 7) * 32 + (lin >> 3);   // XCD swizzle: 2 heads per XCD
  const int pair = sw & 15;
  const int h = sw >> 4;
  const int kh = h >> 3;
  const int wave = tid >> 6, lane = tid & 63;
  const int g = lane >> 4, r = lane & 15;
  const float scale = 0.08838834764831845f;

#pragma unroll
  for (int half = 0; half < 2; ++half) {
    const int qt = half ? (31 - pair) : pair;
    const int qbase = qt * 64;
    __builtin_amdgcn_s_barrier();          // prior tile's LDS readers done
    // stage Q[64][128] (swizzled source, linear dest)
#pragma unroll
    for (int i = 0; i < 4; ++i) {
      int c = i * 256 + tid;
      int row = c >> 4;
      int scol = (((c & 15) ^ (row & 7)) << 3);
      glds16(qbuf + (size_t)(qbase + row) * DMODEL + h * DHEAD + scol,
             &Qs[(i * 256 + (wave << 6)) << 3]);
    }
    f32x4 O[8] = {};
    float mst[4], lst[4];
#pragma unroll
    for (int j = 0; j < 4; ++j) { mst[j] = -1e30f; lst[j] = 0.f; }
    s16x8 aq[4];

    for (int jt = 0; jt <= qt; ++jt) {
      const int jb = jt * 64;
      if (jt) __builtin_amdgcn_s_barrier();  // prev compute done; Ks/Vt free
      // stage K tile [64 j][128 d]
#pragma unroll
      for (int i = 0; i < 4; ++i) {
        int c = i * 256 + tid;
        int row = c >> 4;
        int scol = (((c & 15) ^ (row & 7)) << 3);
        glds16(kbuf + (size_t)(jb + row) * 256 + kh * DHEAD + scol,
               &Ks[(i * 256 + (wave << 6)) << 3]);
      }
      // stage V^T tile [128 d][64 j] from vtb[256][S]
#pragma unroll
      for (int i = 0; i < 4; ++i) {
        int c = i * 256 + tid;
        int row = c >> 3;
        int scol = (((c & 7) ^ (row & 7)) << 3);
        glds16(vtb + (size_t)(kh * 128 + row) * S_LEN + jb + scol,
               &Vt[(i * 256 + (wave << 6)) << 3]);
      }
      asm volatile("s_waitcnt vmcnt(0)" ::: "memory");
      __builtin_amdgcn_s_barrier();
      if (jt == 0) {
#pragma unroll
        for (int kc = 0; kc < 4; ++kc) {
          int rr = wave * 16 + r;
          aq[kc] = *(const s16x8*)&Qs[rr * 128 + ((((kc << 2) | g) ^ (rr & 7)) << 3)];
        }
      }
      // QK^T: sc[n][j] = S[qrow g*4+j][jb + n*16 + r]
      f32x4 sc[4] = {};
      __builtin_amdgcn_s_setprio(1);
#pragma unroll
      for (int n = 0; n < 4; ++n) {
        int rr = n * 16 + r;
#pragma unroll
        for (int kc = 0; kc < 4; ++kc) {
          s16x8 bk = *(const s16x8*)&Ks[rr * 128 + ((((kc << 2) | g) ^ (rr & 7)) << 3)];
          sc[n] = __builtin_amdgcn_mfma_f32_16x16x32_bf16(aq[kc], bk, sc[n], 0, 0, 0);
        }
      }
      __builtin_amdgcn_s_setprio(0);
      // softmax (mask only on diagonal tile)
      if (jt == qt) {
#pragma unroll
        for (int j = 0; j < 4; ++j) {
          int irow = qbase + wave * 16 + g * 4 + j;
#pragma unroll
          for (int n = 0; n < 4; ++n) {
            int jcol = jb + n * 16 + r;
            sc[n][j] = (jcol <= irow) ? sc[n][j] * scale : -1e30f;
          }
        }
      } else {
#pragma unroll
        for (int j = 0; j < 4; ++j)
#pragma unroll
          for (int n = 0; n < 4; ++n) sc[n][j] *= scale;
      }
      float pmax[4], alpha[4], rsum[4];
#pragma unroll
      for (int j = 0; j < 4; ++j)
        pmax[j] = fmaxf(fmaxf(sc[0][j], sc[1][j]), fmaxf(sc[2][j], sc[3][j]));
#pragma unroll
      for (int off = 1; off < 16; off <<= 1)
#pragma unroll
        for (int j = 0; j < 4; ++j) pmax[j] = fmaxf(pmax[j], __shfl_xor(pmax[j], off));
#pragma unroll
      for (int j = 0; j < 4; ++j) {
        float mnew = fmaxf(mst[j], pmax[j]);
        alpha[j] = __expf(mst[j] - mnew);
        mst[j] = mnew;
#pragma unroll
        for (int n = 0; n < 4; ++n) sc[n][j] = __expf(sc[n][j] - mnew);
        rsum[j] = (sc[0][j] + sc[1][j]) + (sc[2][j] + sc[3][j]);
      }
#pragma unroll
      for (int off = 1; off < 16; off <<= 1)
#pragma unroll
        for (int j = 0; j < 4; ++j) rsum[j] += __shfl_xor(rsum[j], off);
#pragma unroll
      for (int j = 0; j < 4; ++j) lst[j] = lst[j] * alpha[j] + rsum[j];
#pragma unroll
      for (int d = 0; d < 8; ++d)
#pragma unroll
        for (int j = 0; j < 4; ++j) O[d][j] *= alpha[j];
      // P -> LDS (wave-private; in-wave ds ordering suffices)
#pragma unroll
      for (int j = 0; j < 4; ++j)
#pragma unroll
        for (int n = 0; n < 4; ++n)
          Ps[wave][g * 4 + j][n * 16 + r] = f2bf(sc[n][j]);
      s16x8 pa0 = *(const s16x8*)&Ps[wave][r][g * 8];
      s16x8 pa1 = *(const s16x8*)&Ps[wave][r][32 + g * 8];
      __builtin_amdgcn_s_setprio(1);
#pragma unroll
      for (int d = 0; d < 8; ++d) {
        int dd = d * 16 + r;
        s16x8 b0 = *(const s16x8*)&Vt[dd * 64 + ((g ^ (dd & 7)) << 3)];
        s16x8 b1 = *(const s16x8*)&Vt[dd * 64 + (((4 + g) ^ (dd & 7)) << 3)];
        O[d] = __builtin_amdgcn_mfma_f32_16x16x32_bf16(pa0, b0, O[d], 0, 0, 0);
        O[d] = __builtin_amdgcn_mfma_f32_16x16x32_bf16(pa1, b1, O[d], 0, 0, 0);
      }
      __builtin_amdgcn_s_setprio(0);
    }
    float linv[4];
#pragma unroll
    for (int j = 0; j < 4; ++j) linv[j] = 1.f / lst[j];
#pragma unroll
    for (int d = 0; d < 8; ++d)
#pragma unroll
      for (int j = 0; j < 4; ++j)
        obuf[(size_t)(qbase + wave * 16 + g * 4 + j) * DMODEL + h * DHEAD + d * 16 + r] =
            f2bf(O[d][j] * linv[j]);
  }
}

// ---------------- host side ----------------
extern "C" void kernel_launch(void* const* d_in, const int* in_sizes, int n_in,
                              void* d_out, int out_size, void* d_ws, size_t ws_size,
                              hipStream_t stream) {
  const int* text = (const int*)d_in[0];
  const float* embed_w = (const float*)d_in[1];
  const float* model_g = (const float*)d_in[2];
  const float* model_b = (const float*)d_in[3];
  const float* blk_g = (const float*)d_in[4];
  const float* blk_b = (const float*)d_in[5];
  const float* attn_g = (const float*)d_in[6];
  const float* attn_b = (const float*)d_in[7];
  const float* wq = (const float*)d_in[8];
  const float* wk = (const float*)d_in[9];
  const float* wv = (const float*)d_in[10];
  const float* wo = (const float*)d_in[11];
  const float* qn_g = (const float*)d_in[12];
  const float* kn_g = (const float*)d_in[13];
  const float* w1 = (const float*)d_in[14];
  const float* b1 = (const float*)d_in[15];
  const float* w2 = (const float*)d_in[16];
  const float* b2 = (const float*)d_in[17];
  const float* head_g = (const float*)d_in[18];
  const float* head_b = (const float*)d_in[19];
  const float* head_w = (const float*)d_in[20];
  const float* head_bias = (const float*)d_in[21];
  float* out = (float*)d_out;

  const size_t SD = (size_t)S_LEN * DMODEL;
  const size_t SKV = (size_t)S_LEN * KVHEAD * DHEAD;
  const size_t SI = (size_t)S_LEN * INNER_DIM;
  const size_t WD = (size_t)DMODEL * DMODEL;
  const size_t WKV = (size_t)DMODEL * KVHEAD * DHEAD;
  const size_t WI = (size_t)DMODEL * INNER_DIM;

  char* p = (char*)d_ws;
  float* xres  = (float*)p; p += SD * 4;
  float* hb    = (float*)p; p += SD * 4;
  float* h2    = (float*)p; p += SD * 4;
  float* qkvf  = (float*)p; p += (size_t)S_LEN * QKVN * 4;
  short* hn16  = (short*)p; p += SD * 2;
  short* h216  = (short*)p; p += SD * 2;
  short* ao16  = (short*)p; p += SD * 2;
  short* ffi16 = (short*)p; p += SI * 2;
  short* qb16  = (short*)p; p += SD * 2;
  short* kb16  = (short*)p; p += SKV * 2;
  short* vt16  = (short*)p; p += SKV * 2;   // V^T [256][S]
  short* wqkvT = (short*)p; p += (size_t)QKVN * DMODEL * 2;
  short* woT   = (short*)p; p += WD * 2;
  short* w1T   = (short*)p; p += WI * 2;
  short* w2T   = (short*)p; p += WI * 2;
  short* headT = w1T;

  dim3 blk(256);
  embed_gather<<<S_LEN, blk, 0, stream>>>(text, embed_w, xres);

  for (int i = 0; i < NLAYER; ++i) {
    const float* wq_i = wq + (size_t)i * WD;
    const float* wk_i = wk + (size_t)i * WKV;
    const float* wv_i = wv + (size_t)i * WKV;
    const float* wo_i = wo + (size_t)i * WD;
    const float* w1_i = w1 + (size_t)i * WI;
    const float* b1_i = b1 + (size_t)i * INNER_DIM;
    const float* w2_i = w2 + (size_t)i * WI;
    const float* b2_i = b2 + (size_t)i * DMODEL;

    wtrans64<<<dim3(32, 32), blk, 0, stream>>>(wq_i, wqkvT, DMODEL, DMODEL, DMODEL);
    wtrans64<<<dim3(4, 32), blk, 0, stream>>>(wk_i, wqkvT + (size_t)2048 * DMODEL, DMODEL, 256, 256);
    wtrans64<<<dim3(4, 32), blk, 0, stream>>>(wv_i, wqkvT + (size_t)2304 * DMODEL, DMODEL, 256, 256);
    wtrans64<<<dim3(32, 32), blk, 0, stream>>>(wo_i, woT, DMODEL, DMODEL, DMODEL);
    wtrans64<<<dim3(128, 32), blk, 0, stream>>>(w1_i, w1T, DMODEL, INNER_DIM, INNER_DIM);
    wtrans64<<<dim3(32, 128), blk, 0, stream>>>(w2_i, w2T, INNER_DIM, DMODEL, DMODEL);

    ln_triple<<<S_LEN, blk, 0, stream>>>(xres, model_g, model_b,
                                         blk_g + i * DMODEL, blk_b + i * DMODEL,
                                         attn_g + i * DMODEL, attn_b + i * DMODEL,
                                         hb, hn16);

    gemm_db<128, 128, 64, 2, 2, 0, false, false, true, false>
        <<<dim3(QKVN / 128, S_LEN / 128), dim3(256), 0, stream>>>(
        hn16, wqkvT, nullptr, nullptr, qkvf, nullptr, S_LEN, QKVN, DMODEL);

    normqk<<<(S_LEN * 18) / 4, blk, 0, stream>>>(qkvf, qn_g + i * DHEAD, kn_g + i * DHEAD, qb16, kb16);
    vtrans<<<dim3(4, 32), blk, 0, stream>>>(qkvf, vt16);

    attn_fwd2<<<dim3(16, 16), blk, 0, stream>>>(qb16, kb16, vt16, ao16);

    gemm_db<128, 128, 64, 2, 2, 0, false, true, true, true>
        <<<dim3(DMODEL / 128, S_LEN / 128), dim3(256), 0, stream>>>(
        ao16, woT, nullptr, hb, h2, h216, S_LEN, DMODEL, DMODEL);
    gemm_8ph<1, true, false, true>
        <<<dim3(INNER_DIM / 256, S_LEN / 256), dim3(512), 0, stream>>>(
        h216, w1T, b1_i, nullptr, ffi16, S_LEN, INNER_DIM, DMODEL);
    gemm_db<128, 128, 64, 2, 2, 0, true, true, true, false>
        <<<dim3(DMODEL / 128, S_LEN / 128), dim3(256), 0, stream>>>(
        ffi16, w2T, b2_i, h2, xres, nullptr, S_LEN, DMODEL, INNER_DIM);
  }

  wtrans64<<<dim3(VOCAB_PAD / 64, 32), blk, 0, stream>>>(head_w, headT, DMODEL, VOCAB, VOCAB_PAD);
  ln_dual<<<S_LEN, blk, 0, stream>>>(xres, model_g, model_b, head_g, head_b, hn16);
  gemm_8ph<0, true, true, false>
      <<<dim3(VOCAB_PAD / 256, S_LEN / 256), dim3(512), 0, stream>>>(
      hn16, headT, head_bias, out, nullptr, S_LEN, VOCAB, DMODEL);
}